// Round 3
// baseline (553.991 us; speedup 1.0000x reference)
//
#include <hip/hip_runtime.h>
#include <math.h>

#define A_W 0.955f
#define B_W 1.3693f
#define INF_W 1e6f
#define HDIM 512
#define WDIM 512
#define NPIX (HDIM*WDIM)
#define NSAMP 16
#define NTOT_F 4194304.0f
#define TST 4        // strip height
#define NSTRIP 128   // strips per sample
#define NBLK (NSAMP*NSTRIP)        // 2048
#define STRIP_COST (4.0f * A_W)    // min cost to propagate a boundary through one strip

// ws layout (bytes):
//  [0,1024):        int cnt[]   ([0..15]=phase1/sample, [16..31]=phase2/sample, [32]=phase3 global)
//  [1024,9216):     int blkflags[2048]  (per strip: bit0=has_fg, bit1=has_bg)
//  [16384,65536):   float sacc[6][2048]
//  [65536,81920):   float mm1[2][2048]  (min,max of Llast rows)
//  [81920,98304):   float mm2[2][2048]  (min,max of Llast2 rows)
//  [1MB,5MB):       float Llast[16][128][512]
//  [5MB,9MB):       float Llast2[16][128][512]
#define OFF_CNT    0
#define OFF_FLAGS  1024
#define OFF_SACC   16384
#define OFF_MM1    65536
#define OFF_MM2    81920
#define OFF_LLAST  (1u<<20)
#define OFF_LLAST2 (5u<<20)

// DPP move with INF fill (floats).
//   WAVE_SHR1 (0x138): lane i <- lane i-1 (== __shfl_up 1)
//   WAVE_SHL1 (0x130): lane i <- lane i+1 (== __shfl_down 1)
template<int CTRL, int RMASK>
__device__ __forceinline__ float dpp_mov_inf(float x) {
    return __int_as_float(__builtin_amdgcn_update_dpp(
        __float_as_int(INF_W), __float_as_int(x), CTRL, RMASK, 0xF, false));
}
template<int CTRL>
__device__ __forceinline__ int dpp_mov0_i(int x) {
    return __builtin_amdgcn_update_dpp(0, x, CTRL, 0xF, 0xF, true);
}

__device__ __forceinline__ float wave_prefix_min_incl(float t) {
    t = fminf(t, dpp_mov_inf<0x111,0xF>(t));
    t = fminf(t, dpp_mov_inf<0x112,0xF>(t));
    t = fminf(t, dpp_mov_inf<0x114,0xF>(t));
    t = fminf(t, dpp_mov_inf<0x118,0xF>(t));
    t = fminf(t, dpp_mov_inf<0x142,0xA>(t));
    t = fminf(t, dpp_mov_inf<0x143,0xC>(t));
    return t;
}

__device__ __forceinline__ void cummin_row(const float* jc, float* v) {
    float g[8];
#pragma unroll
    for (int i = 0; i < 8; ++i) g[i] = v[i] - jc[i];
    float c1[8];
    c1[0] = g[0];
#pragma unroll
    for (int i = 1; i < 8; ++i) c1[i] = fminf(g[i], g[i-1]);
    float c2[8];
    c2[0] = c1[0]; c2[1] = c1[1];
#pragma unroll
    for (int i = 2; i < 8; ++i) c2[i] = fminf(c1[i], c1[i-2]);
    float cj[8];
    cj[0] = c2[0]; cj[1] = c2[1]; cj[2] = c2[2]; cj[3] = c2[3];
#pragma unroll
    for (int i = 4; i < 8; ++i) cj[i] = fminf(c2[i], c2[i-4]);
    float t  = wave_prefix_min_incl(cj[7]);
    float ex = dpp_mov_inf<0x138,0xF>(t);
#pragma unroll
    for (int i = 0; i < 8; ++i) v[i] = jc[i] + fminf(cj[i], ex);
}

__device__ __forceinline__ void row_step(const float* jc, float* prev, const float* drow) {
    float lIn = dpp_mov_inf<0x138,0xF>(prev[7]);
    float rIn = dpp_mov_inf<0x130,0xF>(prev[0]);
    float m[8];
#pragma unroll
    for (int i = 0; i < 8; ++i) {
        float up = prev[i] + A_W;
        float ul = ((i == 0) ? lIn : prev[i-1]) + B_W;
        float ur = ((i == 7) ? rIn : prev[i+1]) + B_W;
        m[i] = fminf(fminf(drow[i], up), fminf(ul, ur));
    }
    cummin_row(jc, m);
#pragma unroll
    for (int i = 0; i < 8; ++i) prev[i] = m[i];
}

// 4 fused T3 steps (exact, INF outside grid). T3^4 == one call (TST==4).
__device__ __forceinline__ void t3x4(float* b) {
    float e[16];
#pragma unroll
    for (int k = 0; k < 4; ++k) e[k]    = dpp_mov_inf<0x138,0xF>(b[4+k]);
#pragma unroll
    for (int k = 0; k < 8; ++k) e[4+k]  = b[k];
#pragma unroll
    for (int k = 0; k < 4; ++k) e[12+k] = dpp_mov_inf<0x130,0xF>(b[k]);
    const float w0 = 4.f*A_W, w1 = 3.f*A_W + B_W, w2 = 2.f*A_W + 2.f*B_W;
    const float w3 = A_W + 3.f*B_W, w4 = 4.f*B_W;
#pragma unroll
    for (int i = 0; i < 8; ++i) {
        float m = e[i+4] + w0;
        m = fminf(m, fminf(e[i+3], e[i+5]) + w1);
        m = fminf(m, fminf(e[i+2], e[i+6]) + w2);
        m = fminf(m, fminf(e[i+1], e[i+7]) + w3);
        m = fminf(m, fminf(e[i+0], e[i+8]) + w4);
        b[i] = m;
    }
}

struct RowBits { int efg; int ebg; int rawbg; };

__device__ __forceinline__ RowBits make_rowbits(uint4 a, uint4 b) {
    int fg = ((a.x!=0u)?1:0) | ((a.y!=0u)?2:0) | ((a.z!=0u)?4:0) | ((a.w!=0u)?8:0)
           | ((b.x!=0u)?16:0) | ((b.y!=0u)?32:0) | ((b.z!=0u)?64:0) | ((b.w!=0u)?128:0);
    int bg = (~fg) & 0xFF;
    int lf = dpp_mov0_i<0x138>(fg), rf = dpp_mov0_i<0x130>(fg);
    int lb = dpp_mov0_i<0x138>(bg), rb = dpp_mov0_i<0x130>(bg);
    RowBits r;
    r.efg = (fg | (fg<<1) | (fg>>1) | ((lf>>7)&1) | ((rf&1)<<7)) & 0xFF;
    r.ebg = (bg | (bg<<1) | (bg>>1) | ((lb>>7)&1) | ((rb&1)<<7)) & 0xFF;
    r.rawbg = bg;
    return r;
}

__device__ __forceinline__ RowBits loadrow_bits(const int* tgb, int rr, int c0) {
    if (rr < 0 || rr >= HDIM) { RowBits z; z.efg = 0; z.ebg = 0; z.rawbg = 0; return z; }
    const uint4* p = (const uint4*)(tgb + (size_t)rr * WDIM + c0);
    return make_rowbits(p[0], p[1]);
}

// store min/max of an L row (prev[8] across wave) into mm arrays
__device__ __forceinline__ void store_minmax(const float* prev, float* __restrict__ mm,
                                             int idx, int lane) {
    float mn = prev[0], mx = prev[0];
#pragma unroll
    for (int i = 1; i < 8; ++i) { mn = fminf(mn, prev[i]); mx = fmaxf(mx, prev[i]); }
#pragma unroll
    for (int off = 32; off > 0; off >>= 1) {
        mn = fminf(mn, __shfl_xor(mn, off));
        mx = fmaxf(mx, __shfl_xor(mx, off));
    }
    if (lane == 0) { mm[idx] = mn; mm[NBLK + idx] = mx; }
}

// Inline exact boundary with dominance pruning over up to 127 strips (two 64-wide
// ballot segments). Strip k skippable when minL[k] + STRIP_COST*(n-1-k) > maxL[n-1]
// (each propagated row adds >= A; b*[j] <= L[n-1][j] <= maxL[n-1]). Ties kept -> exact.
__device__ __forceinline__ void inline_bounds(const float* __restrict__ Lb, int n,
                                              const float* jc, int c0, float* prev,
                                              const float* __restrict__ mm, int base,
                                              int lane) {
    float ub = mm[NBLK + base + (n - 1)];                // maxL[n-1]
    int k0 = n - 1;
    {
        int k = lane;
        bool c = (k < n) && (mm[base + k] + STRIP_COST * (float)(n - 1 - k) <= ub);
        unsigned long long m0 = __ballot((int)c);
        if (m0 != 0ull) {
            k0 = __ffsll((long long)m0) - 1;
        } else if (n > 64) {
            k = 64 + lane;
            bool c1 = (k < n) && (mm[base + k] + STRIP_COST * (float)(n - 1 - k) <= ub);
            unsigned long long m1 = __ballot((int)c1);
            if (m1 != 0ull) k0 = 64 + __ffsll((long long)m1) - 1;
        }
    }

    float b[8];
    const float* Lr = Lb + (size_t)k0 * WDIM + c0;
    float4 l0 = *(const float4*)Lr;
    float4 l1 = *(const float4*)(Lr + 4);
    b[0]=l0.x; b[1]=l0.y; b[2]=l0.z; b[3]=l0.w;
    b[4]=l1.x; b[5]=l1.y; b[6]=l1.z; b[7]=l1.w;
    for (int sg = k0 + 1; sg < n; ++sg) {
        const float* Ls = Lb + (size_t)sg * WDIM + c0;
        float4 m0 = *(const float4*)Ls;
        float4 m1 = *(const float4*)(Ls + 4);
        t3x4(b);                                 // T3^4 exact (TST==4)
        cummin_row(jc, b);
        b[0]=fminf(b[0],m0.x); b[1]=fminf(b[1],m0.y); b[2]=fminf(b[2],m0.z); b[3]=fminf(b[3],m0.w);
        b[4]=fminf(b[4],m1.x); b[5]=fminf(b[5],m1.y); b[6]=fminf(b[6],m1.z); b[7]=fminf(b[7],m1.w);
    }
#pragma unroll
    for (int i = 0; i < 8; ++i) prev[i] = b[i];
}

// ---- inter-block sync WITHOUT cooperative launch.
// Co-residency by construction: __launch_bounds__(64,4) caps VGPR at 128 -> 16
// blocks/CU; LDS 8KB -> 20/CU; capacity 16*256 = 4096 >= 2048 blocks, so every
// workgroup is resident and the spins cannot deadlock (verified: previous run
// completed, no hang).
// IMPORTANT: release_add must be called by ONE lane only (each block contributes
// exactly +1; a wave-wide call adds 64 and releases waiters ~64x early — that was
// round 2's absmax failure). The release fence (s_waitcnt vmcnt(0) + L2 writeback)
// is wave-level, not exec-masked, so a lane-0 release still covers all 64 lanes'
// prior stores.
__device__ __forceinline__ void release_add(int* p) {
    __hip_atomic_fetch_add(p, 1, __ATOMIC_RELEASE, __HIP_MEMORY_SCOPE_AGENT);
}
__device__ __forceinline__ void acquire_wait(int* p, int target) {
    while (__hip_atomic_load(p, __ATOMIC_RELAXED, __HIP_MEMORY_SCOPE_AGENT) < target)
        __builtin_amdgcn_s_sleep(2);
    int v = __hip_atomic_load(p, __ATOMIC_ACQUIRE, __HIP_MEMORY_SCOPE_AGENT);
    asm volatile("" :: "v"(v));   // keep the acquire load alive
}

// =====================================================================================
// Fused kernel: all 3 strip phases + final reduce in ONE dispatch.
//  - per-sample counters replace 2 kernel boundaries (samples pipeline independently)
//  - block (s,sig) handles flipped strip 127-sig in phase 3 => its pass-2 rows are
//    exactly the pass-1 rows it computed in phase 2 (still in its LDS) => dB eliminated
//  - tg bits (smask, rawbg) kept in registers across phases => tg read once, not 3x;
//    phase-3 target bits come from __shfl(rawbg, 63-lane) (column reversal)
// =====================================================================================
__global__ __launch_bounds__(64, 4) void fused_kernel(
        const float* __restrict__ pred, const int* __restrict__ tg,
        const float* __restrict__ lv, float* __restrict__ out,
        float* __restrict__ Llast, float* __restrict__ mm1, int* __restrict__ blkflags,
        float* __restrict__ Llast2, float* __restrict__ mm2, float* __restrict__ sacc,
        int* cnt) {
    const int s = blockIdx.x >> 7, sig = blockIdx.x & 127;
    const int lane = threadIdx.x;
    const int c0 = lane * 8;
    const int* tgb = tg + (size_t)s * NPIX;
    const int R0 = sig * TST;
    float jc[8];
#pragma unroll
    for (int i = 0; i < 8; ++i) jc[i] = A_W * (float)(c0 + i);

    __shared__ float lds[TST][WDIM];   // 8 KB; single-wave block

    // ---------------- phase 1: local strip scan (INF incoming) -> Llast/mm1/flags
    int smaskv[TST], rawbgv[TST];
    RowBits rA = loadrow_bits(tgb, R0 - 1, c0);
    RowBits rB = loadrow_bits(tgb, R0, c0);
    float prev[8];
#pragma unroll
    for (int i = 0; i < 8; ++i) prev[i] = INF_W;
    int fgor = 0, bgor = 0;
#pragma unroll
    for (int t = 0; t < TST; ++t) {
        RowBits rC = loadrow_bits(tgb, R0 + t + 1, c0);
        fgor |= (~rB.rawbg) & 0xFF;
        bgor |= rB.rawbg;
        int smask = (rA.efg | rB.efg | rC.efg) & (rA.ebg | rB.ebg | rC.ebg);
        smaskv[t] = smask;
        rawbgv[t] = rB.rawbg;
        float dr[8];
#pragma unroll
        for (int i = 0; i < 8; ++i) dr[i] = ((smask >> i) & 1) ? 0.f : INF_W;
        row_step(jc, prev, dr);
        rA = rB; rB = rC;
    }
    {
        float* Lr = Llast + ((size_t)s * NSTRIP + sig) * WDIM + c0;
        *(float4*)Lr       = make_float4(prev[0], prev[1], prev[2], prev[3]);
        *(float4*)(Lr + 4) = make_float4(prev[4], prev[5], prev[6], prev[7]);
        store_minmax(prev, mm1, s * NSTRIP + sig, lane);
        int wf = __any(fgor != 0) ? 1 : 0;
        int wb = __any(bgor != 0) ? 2 : 0;
        if (lane == 0) blkflags[blockIdx.x] = wf | wb;
    }
    if (lane == 0) release_add(&cnt[s]);

    // ---------------- phase 2: exact pass-1 rows -> LDS; flipped local scan -> Llast2/mm2
    acquire_wait(&cnt[s], NSTRIP);
    if (sig == 0) {
#pragma unroll
        for (int i = 0; i < 8; ++i) prev[i] = INF_W;
    } else {
        inline_bounds(Llast + (size_t)s * NSTRIP * WDIM, sig, jc, c0, prev,
                      mm1, s * NSTRIP, lane);
    }
#pragma unroll
    for (int t = 0; t < TST; ++t) {
        float dr[8];
#pragma unroll
        for (int i = 0; i < 8; ++i) dr[i] = ((smaskv[t] >> i) & 1) ? 0.f : INF_W;
        row_step(jc, prev, dr);
        *(float4*)&lds[t][c0]     = make_float4(prev[0], prev[1], prev[2], prev[3]);
        *(float4*)&lds[t][c0 + 4] = make_float4(prev[4], prev[5], prev[6], prev[7]);
    }
    __syncthreads();
    // flipped (pass-2) local scan over this strip, INF incoming
#pragma unroll
    for (int i = 0; i < 8; ++i) prev[i] = INF_W;
#pragma unroll
    for (int t2 = 0; t2 < TST; ++t2) {
        float4 a = *(const float4*)&lds[TST - 1 - t2][504 - c0];
        float4 q = *(const float4*)&lds[TST - 1 - t2][508 - c0];
        float dr[8];
        dr[7]=a.x; dr[6]=a.y; dr[5]=a.z; dr[4]=a.w;
        dr[3]=q.x; dr[2]=q.y; dr[1]=q.z; dr[0]=q.w;
        row_step(jc, prev, dr);
    }
    const int sig2 = NSTRIP - 1 - sig;   // flipped strip index == this block's own rows
    {
        float* Lr = Llast2 + ((size_t)s * NSTRIP + sig2) * WDIM + c0;
        *(float4*)Lr       = make_float4(prev[0], prev[1], prev[2], prev[3]);
        *(float4*)(Lr + 4) = make_float4(prev[4], prev[5], prev[6], prev[7]);
        store_minmax(prev, mm2, s * NSTRIP + sig2, lane);
    }
    if (lane == 0) release_add(&cnt[NSAMP + s]);

    // ---------------- phase 3: exact pass-2 rows (dr from own LDS) + fused loss -> sacc
    acquire_wait(&cnt[NSAMP + s], NSTRIP);
    if (sig2 == 0) {
#pragma unroll
        for (int i = 0; i < 8; ++i) prev[i] = INF_W;
    } else {
        inline_bounds(Llast2 + (size_t)s * NSTRIP * WDIM, sig2, jc, c0, prev,
                      mm2, s * NSTRIP, lane);
    }
    const size_t sb = (size_t)s * NPIX;
    float mx = 0.f, facc = 0.f, s1 = 0.f, s2 = 0.f, iacc = 0.f, pacc = 0.f;
#pragma unroll
    for (int t = 0; t < TST; ++t) {
        const int pr = R0 + (TST - 1) - t;        // == HDIM-1-(sig2*TST+t), own strip rows
        float4 a  = *(const float4*)&lds[TST - 1 - t][504 - c0];
        float4 b4 = *(const float4*)&lds[TST - 1 - t][508 - c0];
        float dr[8];
        dr[7]=a.x;  dr[6]=a.y;  dr[5]=a.z;  dr[4]=a.w;
        dr[3]=b4.x; dr[2]=b4.y; dr[1]=b4.z; dr[0]=b4.w;
        const size_t rbase = sb + (size_t)pr * WDIM + (WDIM - 8 - c0);
        float4 xa = *(const float4*)(pred + rbase);
        float4 xb = *(const float4*)(pred + rbase + 4);
        float px[8];
        px[7]=xa.x; px[6]=xa.y; px[5]=xa.z; px[4]=xa.w;
        px[3]=xb.x; px[2]=xb.y; px[1]=xb.z; px[0]=xb.w;
        // target bits for reversed columns: col 511-c0-i lives in lane 63-lane, bit 7-i
        int sh = __shfl(rawbgv[TST - 1 - t], 63 - lane);
        row_step(jc, prev, dr);
#pragma unroll
        for (int i = 0; i < 8; ++i) {
            float x = px[i];
            float dd = prev[i];
            float e = __expf(-fabsf(x));
            float inv = 1.f / (1.f + e);
            float pr_ = (x >= 0.f) ? inv : (1.f - inv);   // sigmoid(x)
            float L = __logf(1.f + e);                    // softplus(-|x|)
            bool t1 = ((sh >> (7 - i)) & 1) == 0;         // fg pixel
            float fo = t1 ? 0.25f * (1.f - pr_) * (1.f - pr_) * (fmaxf(-x, 0.f) + L)
                          : 0.75f * pr_ * pr_ * (fmaxf(x, 0.f) + L);
            facc += fo;
            float base = t1 ? (1.f - pr_) : pr_;
            s1 += base;
            s2 += base * dd;
            float tf = t1 ? 1.f : 0.f;
            iacc += tf * pr_;
            pacc += pr_ + tf;
            mx = fmaxf(mx, dd);
        }
    }
#pragma unroll
    for (int off = 32; off > 0; off >>= 1) {
        facc += __shfl_xor(facc, off);
        s1   += __shfl_xor(s1, off);
        s2   += __shfl_xor(s2, off);
        iacc += __shfl_xor(iacc, off);
        pacc += __shfl_xor(pacc, off);
        mx    = fmaxf(mx, __shfl_xor(mx, off));
    }
    if (lane == 0) {
        const int idx = s * NSTRIP + sig2;
        sacc[0 * NBLK + idx] = s1;
        sacc[1 * NBLK + idx] = s2;
        sacc[2 * NBLK + idx] = iacc;
        sacc[3 * NBLK + idx] = pacc;
        sacc[4 * NBLK + idx] = mx;
        sacc[5 * NBLK + idx] = facc;
    }
    if (lane == 0) release_add(&cnt[2 * NSAMP]);

    // ---------------- phase 4: final reduction in block 0 only
    if (blockIdx.x != 0) return;
    acquire_wait(&cnt[2 * NSAMP], NBLK);
    float fsum = 0.f, bsum = 0.f, dsum = 0.f, isum = 0.f;
    for (int ss = 0; ss < NSAMP; ++ss) {
        int i0 = ss * NSTRIP + lane, i1 = i0 + 64;
        float t1 = sacc[0 * NBLK + i0] + sacc[0 * NBLK + i1];
        float t2 = sacc[1 * NBLK + i0] + sacc[1 * NBLK + i1];
        float ia = sacc[2 * NBLK + i0] + sacc[2 * NBLK + i1];
        float pa = sacc[3 * NBLK + i0] + sacc[3 * NBLK + i1];
        float mxs = fmaxf(sacc[4 * NBLK + i0], sacc[4 * NBLK + i1]);
        float fa = sacc[5 * NBLK + i0] + sacc[5 * NBLK + i1];
        int   vv = blkflags[i0] | blkflags[i1];
#pragma unroll
        for (int off = 32; off > 0; off >>= 1) {
            t1 += __shfl_xor(t1, off);
            t2 += __shfl_xor(t2, off);
            ia += __shfl_xor(ia, off);
            pa += __shfl_xor(pa, off);
            fa += __shfl_xor(fa, off);
            mxs = fmaxf(mxs, __shfl_xor(mxs, off));
            vv |= __shfl_xor(vv, off);
        }
        bool hasb = (vv & 3) == 3;     // boundary nonempty (has_fg && has_bg)
        fsum += fa;
        float distsum = hasb ? ((mxs > 0.f) ? t2 / fmaxf(mxs, 1e-12f) : 0.f) : t1;
        bsum += t1 + distsum;
        dsum += (2.f * ia + 1e-6f) / (pa + 1e-6f);
        isum += (ia + 1e-6f) / (pa - ia + 1e-6f);
    }
    if (lane == 0) {
        float focal = fsum / NTOT_F;
        float bnd   = bsum / NTOT_F;
        float dice = 1.f - dsum / 16.f;
        float iou  = 1.f - isum / 16.f;
        float l0 = lv[0], l1 = lv[1], l2 = lv[2], l3 = lv[3];
        float total = expf(-l0) * focal + l0 + expf(-l1) * dice + l1
                    + expf(-l2) * bnd  + l2 + expf(-l3) * iou  + l3;
        out[0] = total; out[1] = focal; out[2] = dice; out[3] = bnd; out[4] = iou;
    }
}

extern "C" void kernel_launch(void* const* d_in, const int* in_sizes, int n_in,
                              void* d_out, int out_size, void* d_ws, size_t ws_size,
                              hipStream_t stream) {
    const float* pred = (const float*)d_in[0];
    const int*   tg   = (const int*)d_in[1];
    const float* lv   = (const float*)d_in[2];
    float* out = (float*)d_out;
    char* ws = (char*)d_ws;
    int*   cnt      = (int*)(ws + OFF_CNT);
    int*   blkflags = (int*)(ws + OFF_FLAGS);
    float* sacc     = (float*)(ws + OFF_SACC);
    float* mm1      = (float*)(ws + OFF_MM1);
    float* mm2      = (float*)(ws + OFF_MM2);
    float* Llast    = (float*)(ws + OFF_LLAST);
    float* Llast2   = (float*)(ws + OFF_LLAST2);

    // ws is poisoned between iterations -> sync counters must be zeroed each launch.
    // hipMemsetAsync is graph-capturable; single unconditional code path.
    hipMemsetAsync(cnt, 0, 256, stream);
    fused_kernel<<<NBLK, 64, 0, stream>>>(pred, tg, lv, out, Llast, mm1, blkflags,
                                          Llast2, mm2, sacc, cnt);
}

// Round 4
// 490.319 us; speedup vs baseline: 1.1299x; 1.1299x over previous
//
#include <hip/hip_runtime.h>
#include <math.h>

#define A_W 0.955f
#define B_W 1.3693f
#define INF_W 1e6f
#define HDIM 512
#define WDIM 512
#define NPIX (HDIM*WDIM)
#define NSAMP 16
#define NTOT_F 4194304.0f
#define TST 4        // strip height
#define NSTRIP 128   // strips per sample
#define NBLK (NSAMP*NSTRIP)        // 2048
#define STRIP_COST (4.0f * A_W)    // min cost to propagate a boundary through one strip

// ws layout (bytes):
//  [0,1024):        int cnt[]   ([0..15]=phase1/sample, [16..31]=phase2/sample, [32]=phase3 global)
//  [1024,9216):     int blkflags[2048]  (per strip: bit0=has_fg, bit1=has_bg)
//  [16384,65536):   float sacc[6][2048]
//  [65536,81920):   float mm1[2][2048]  (min,max of Llast rows)
//  [81920,98304):   float mm2[2][2048]  (min,max of Llast2 rows)
//  [1MB,5MB):       float Llast[16][128][512]
//  [5MB,9MB):       float Llast2[16][128][512]
#define OFF_CNT    0
#define OFF_FLAGS  1024
#define OFF_SACC   16384
#define OFF_MM1    65536
#define OFF_MM2    81920
#define OFF_LLAST  (1u<<20)
#define OFF_LLAST2 (5u<<20)

// DPP move with INF fill (floats).
//   WAVE_SHR1 (0x138): lane i <- lane i-1 (== __shfl_up 1)
//   WAVE_SHL1 (0x130): lane i <- lane i+1 (== __shfl_down 1)
template<int CTRL, int RMASK>
__device__ __forceinline__ float dpp_mov_inf(float x) {
    return __int_as_float(__builtin_amdgcn_update_dpp(
        __float_as_int(INF_W), __float_as_int(x), CTRL, RMASK, 0xF, false));
}
template<int CTRL>
__device__ __forceinline__ int dpp_mov0_i(int x) {
    return __builtin_amdgcn_update_dpp(0, x, CTRL, 0xF, 0xF, true);
}

__device__ __forceinline__ float wave_prefix_min_incl(float t) {
    t = fminf(t, dpp_mov_inf<0x111,0xF>(t));
    t = fminf(t, dpp_mov_inf<0x112,0xF>(t));
    t = fminf(t, dpp_mov_inf<0x114,0xF>(t));
    t = fminf(t, dpp_mov_inf<0x118,0xF>(t));
    t = fminf(t, dpp_mov_inf<0x142,0xA>(t));
    t = fminf(t, dpp_mov_inf<0x143,0xC>(t));
    return t;
}

__device__ __forceinline__ void cummin_row(const float* jc, float* v) {
    float g[8];
#pragma unroll
    for (int i = 0; i < 8; ++i) g[i] = v[i] - jc[i];
    float c1[8];
    c1[0] = g[0];
#pragma unroll
    for (int i = 1; i < 8; ++i) c1[i] = fminf(g[i], g[i-1]);
    float c2[8];
    c2[0] = c1[0]; c2[1] = c1[1];
#pragma unroll
    for (int i = 2; i < 8; ++i) c2[i] = fminf(c1[i], c1[i-2]);
    float cj[8];
    cj[0] = c2[0]; cj[1] = c2[1]; cj[2] = c2[2]; cj[3] = c2[3];
#pragma unroll
    for (int i = 4; i < 8; ++i) cj[i] = fminf(c2[i], c2[i-4]);
    float t  = wave_prefix_min_incl(cj[7]);
    float ex = dpp_mov_inf<0x138,0xF>(t);
#pragma unroll
    for (int i = 0; i < 8; ++i) v[i] = jc[i] + fminf(cj[i], ex);
}

__device__ __forceinline__ void row_step(const float* jc, float* prev, const float* drow) {
    float lIn = dpp_mov_inf<0x138,0xF>(prev[7]);
    float rIn = dpp_mov_inf<0x130,0xF>(prev[0]);
    float m[8];
#pragma unroll
    for (int i = 0; i < 8; ++i) {
        float up = prev[i] + A_W;
        float ul = ((i == 0) ? lIn : prev[i-1]) + B_W;
        float ur = ((i == 7) ? rIn : prev[i+1]) + B_W;
        m[i] = fminf(fminf(drow[i], up), fminf(ul, ur));
    }
    cummin_row(jc, m);
#pragma unroll
    for (int i = 0; i < 8; ++i) prev[i] = m[i];
}

// 4 fused T3 steps (exact, INF outside grid). T3^4 == one call (TST==4).
__device__ __forceinline__ void t3x4(float* b) {
    float e[16];
#pragma unroll
    for (int k = 0; k < 4; ++k) e[k]    = dpp_mov_inf<0x138,0xF>(b[4+k]);
#pragma unroll
    for (int k = 0; k < 8; ++k) e[4+k]  = b[k];
#pragma unroll
    for (int k = 0; k < 4; ++k) e[12+k] = dpp_mov_inf<0x130,0xF>(b[k]);
    const float w0 = 4.f*A_W, w1 = 3.f*A_W + B_W, w2 = 2.f*A_W + 2.f*B_W;
    const float w3 = A_W + 3.f*B_W, w4 = 4.f*B_W;
#pragma unroll
    for (int i = 0; i < 8; ++i) {
        float m = e[i+4] + w0;
        m = fminf(m, fminf(e[i+3], e[i+5]) + w1);
        m = fminf(m, fminf(e[i+2], e[i+6]) + w2);
        m = fminf(m, fminf(e[i+1], e[i+7]) + w3);
        m = fminf(m, fminf(e[i+0], e[i+8]) + w4);
        b[i] = m;
    }
}

struct RowBits { int efg; int ebg; int rawbg; };

__device__ __forceinline__ RowBits make_rowbits(uint4 a, uint4 b) {
    int fg = ((a.x!=0u)?1:0) | ((a.y!=0u)?2:0) | ((a.z!=0u)?4:0) | ((a.w!=0u)?8:0)
           | ((b.x!=0u)?16:0) | ((b.y!=0u)?32:0) | ((b.z!=0u)?64:0) | ((b.w!=0u)?128:0);
    int bg = (~fg) & 0xFF;
    int lf = dpp_mov0_i<0x138>(fg), rf = dpp_mov0_i<0x130>(fg);
    int lb = dpp_mov0_i<0x138>(bg), rb = dpp_mov0_i<0x130>(bg);
    RowBits r;
    r.efg = (fg | (fg<<1) | (fg>>1) | ((lf>>7)&1) | ((rf&1)<<7)) & 0xFF;
    r.ebg = (bg | (bg<<1) | (bg>>1) | ((lb>>7)&1) | ((rb&1)<<7)) & 0xFF;
    r.rawbg = bg;
    return r;
}

__device__ __forceinline__ RowBits loadrow_bits(const int* tgb, int rr, int c0) {
    if (rr < 0 || rr >= HDIM) { RowBits z; z.efg = 0; z.ebg = 0; z.rawbg = 0; return z; }
    const uint4* p = (const uint4*)(tgb + (size_t)rr * WDIM + c0);
    return make_rowbits(p[0], p[1]);
}

// store min/max of an L row (prev[8] across wave) into mm arrays
__device__ __forceinline__ void store_minmax(const float* prev, float* __restrict__ mm,
                                             int idx, int lane) {
    float mn = prev[0], mx = prev[0];
#pragma unroll
    for (int i = 1; i < 8; ++i) { mn = fminf(mn, prev[i]); mx = fmaxf(mx, prev[i]); }
#pragma unroll
    for (int off = 32; off > 0; off >>= 1) {
        mn = fminf(mn, __shfl_xor(mn, off));
        mx = fmaxf(mx, __shfl_xor(mx, off));
    }
    if (lane == 0) { mm[idx] = mn; mm[NBLK + idx] = mx; }
}

// Inline exact boundary with dominance pruning over up to 127 strips (two 64-wide
// ballot segments). Strip k skippable when minL[k] + STRIP_COST*(n-1-k) > maxL[n-1]
// (each propagated row adds >= A; b*[j] <= L[n-1][j] <= maxL[n-1]). Ties kept -> exact.
__device__ __forceinline__ void inline_bounds(const float* __restrict__ Lb, int n,
                                              const float* jc, int c0, float* prev,
                                              const float* __restrict__ mm, int base,
                                              int lane) {
    float ub = mm[NBLK + base + (n - 1)];                // maxL[n-1]
    int k0 = n - 1;
    {
        int k = lane;
        bool c = (k < n) && (mm[base + k] + STRIP_COST * (float)(n - 1 - k) <= ub);
        unsigned long long m0 = __ballot((int)c);
        if (m0 != 0ull) {
            k0 = __ffsll((long long)m0) - 1;
        } else if (n > 64) {
            k = 64 + lane;
            bool c1 = (k < n) && (mm[base + k] + STRIP_COST * (float)(n - 1 - k) <= ub);
            unsigned long long m1 = __ballot((int)c1);
            if (m1 != 0ull) k0 = 64 + __ffsll((long long)m1) - 1;
        }
    }

    float b[8];
    const float* Lr = Lb + (size_t)k0 * WDIM + c0;
    float4 l0 = *(const float4*)Lr;
    float4 l1 = *(const float4*)(Lr + 4);
    b[0]=l0.x; b[1]=l0.y; b[2]=l0.z; b[3]=l0.w;
    b[4]=l1.x; b[5]=l1.y; b[6]=l1.z; b[7]=l1.w;
    for (int sg = k0 + 1; sg < n; ++sg) {
        const float* Ls = Lb + (size_t)sg * WDIM + c0;
        float4 m0 = *(const float4*)Ls;
        float4 m1 = *(const float4*)(Ls + 4);
        t3x4(b);                                 // T3^4 exact (TST==4)
        cummin_row(jc, b);
        b[0]=fminf(b[0],m0.x); b[1]=fminf(b[1],m0.y); b[2]=fminf(b[2],m0.z); b[3]=fminf(b[3],m0.w);
        b[4]=fminf(b[4],m1.x); b[5]=fminf(b[5],m1.y); b[6]=fminf(b[6],m1.z); b[7]=fminf(b[7],m1.w);
    }
#pragma unroll
    for (int i = 0; i < 8; ++i) prev[i] = b[i];
}

// ---- inter-block sync WITHOUT cooperative launch.
// Co-residency by construction: __launch_bounds__(64,2) caps VGPR at 256; ANY
// VGPR<=256 gives >=2 waves/SIMD -> >=8 single-wave blocks/CU -> >=2048 slots =
// grid size. LDS 8KB -> 20/CU, not binding. So every workgroup is resident and
// the spins cannot deadlock (round-3 run confirmed completion at even tighter
// bounds). NOTE: round-3 post-mortem — (64,4) squeezed VGPR to 64 and spilled
// ~90MB of scratch traffic (WRITE_SIZE 75MB vs 8MB expected), 490us. The cap
// must stay at 256 (2 waves/SIMD) for this kernel's register footprint.
// release_add: ONE lane per block (wave-wide add releases waiters 64x early —
// round-2's absmax failure). The release fence is wave-level, not exec-masked,
// so lane-0 release covers all 64 lanes' prior stores.
__device__ __forceinline__ void release_add(int* p) {
    __hip_atomic_fetch_add(p, 1, __ATOMIC_RELEASE, __HIP_MEMORY_SCOPE_AGENT);
}
__device__ __forceinline__ void acquire_wait(int* p, int target) {
    while (__hip_atomic_load(p, __ATOMIC_RELAXED, __HIP_MEMORY_SCOPE_AGENT) < target)
        __builtin_amdgcn_s_sleep(8);
    int v = __hip_atomic_load(p, __ATOMIC_ACQUIRE, __HIP_MEMORY_SCOPE_AGENT);
    asm volatile("" :: "v"(v));   // keep the acquire load alive
}

// =====================================================================================
// Fused kernel: all 3 strip phases + final reduce in ONE dispatch.
//  - per-sample counters replace 2 kernel boundaries (samples pipeline independently)
//  - block (s,sig) handles flipped strip 127-sig in phase 3 => its pass-2 rows are
//    exactly the pass-1 rows it computed in phase 2 (still in its LDS) => dB eliminated
//  - tg bits kept packed in 2 ints across phases (byte t = strip row t) => tg read
//    once; phase-3 target bits come from __shfl(byte, 63-lane) (column reversal)
// =====================================================================================
__global__ __launch_bounds__(64, 2) void fused_kernel(
        const float* __restrict__ pred, const int* __restrict__ tg,
        const float* __restrict__ lv, float* __restrict__ out,
        float* __restrict__ Llast, float* __restrict__ mm1, int* __restrict__ blkflags,
        float* __restrict__ Llast2, float* __restrict__ mm2, float* __restrict__ sacc,
        int* cnt) {
    const int s = blockIdx.x >> 7, sig = blockIdx.x & 127;
    const int lane = threadIdx.x;
    const int c0 = lane * 8;
    const int* tgb = tg + (size_t)s * NPIX;
    const int R0 = sig * TST;
    float jc[8];
#pragma unroll
    for (int i = 0; i < 8; ++i) jc[i] = A_W * (float)(c0 + i);

    __shared__ float lds[TST][WDIM];   // 8 KB; single-wave block

    // ---------------- phase 1: local strip scan (INF incoming) -> Llast/mm1/flags
    unsigned int smaskp = 0u, rawbgp = 0u;   // byte t = row t's 8-bit masks
    RowBits rA = loadrow_bits(tgb, R0 - 1, c0);
    RowBits rB = loadrow_bits(tgb, R0, c0);
    float prev[8];
#pragma unroll
    for (int i = 0; i < 8; ++i) prev[i] = INF_W;
    int fgor = 0, bgor = 0;
#pragma unroll
    for (int t = 0; t < TST; ++t) {
        RowBits rC = loadrow_bits(tgb, R0 + t + 1, c0);
        fgor |= (~rB.rawbg) & 0xFF;
        bgor |= rB.rawbg;
        int smask = (rA.efg | rB.efg | rC.efg) & (rA.ebg | rB.ebg | rC.ebg);
        smaskp |= ((unsigned int)smask) << (8 * t);
        rawbgp |= ((unsigned int)rB.rawbg) << (8 * t);
        float dr[8];
#pragma unroll
        for (int i = 0; i < 8; ++i) dr[i] = ((smask >> i) & 1) ? 0.f : INF_W;
        row_step(jc, prev, dr);
        rA = rB; rB = rC;
    }
    {
        float* Lr = Llast + ((size_t)s * NSTRIP + sig) * WDIM + c0;
        *(float4*)Lr       = make_float4(prev[0], prev[1], prev[2], prev[3]);
        *(float4*)(Lr + 4) = make_float4(prev[4], prev[5], prev[6], prev[7]);
        store_minmax(prev, mm1, s * NSTRIP + sig, lane);
        int wf = __any(fgor != 0) ? 1 : 0;
        int wb = __any(bgor != 0) ? 2 : 0;
        if (lane == 0) blkflags[blockIdx.x] = wf | wb;
    }
    if (lane == 0) release_add(&cnt[s]);

    // ---------------- phase 2: exact pass-1 rows -> LDS; flipped local scan -> Llast2/mm2
    acquire_wait(&cnt[s], NSTRIP);
    if (sig == 0) {
#pragma unroll
        for (int i = 0; i < 8; ++i) prev[i] = INF_W;
    } else {
        inline_bounds(Llast + (size_t)s * NSTRIP * WDIM, sig, jc, c0, prev,
                      mm1, s * NSTRIP, lane);
    }
#pragma unroll
    for (int t = 0; t < TST; ++t) {
        unsigned int sm = (smaskp >> (8 * t)) & 0xFFu;
        float dr[8];
#pragma unroll
        for (int i = 0; i < 8; ++i) dr[i] = ((sm >> i) & 1u) ? 0.f : INF_W;
        row_step(jc, prev, dr);
        *(float4*)&lds[t][c0]     = make_float4(prev[0], prev[1], prev[2], prev[3]);
        *(float4*)&lds[t][c0 + 4] = make_float4(prev[4], prev[5], prev[6], prev[7]);
    }
    __syncthreads();
    // flipped (pass-2) local scan over this strip, INF incoming
#pragma unroll
    for (int i = 0; i < 8; ++i) prev[i] = INF_W;
#pragma unroll
    for (int t2 = 0; t2 < TST; ++t2) {
        float4 a = *(const float4*)&lds[TST - 1 - t2][504 - c0];
        float4 q = *(const float4*)&lds[TST - 1 - t2][508 - c0];
        float dr[8];
        dr[7]=a.x; dr[6]=a.y; dr[5]=a.z; dr[4]=a.w;
        dr[3]=q.x; dr[2]=q.y; dr[1]=q.z; dr[0]=q.w;
        row_step(jc, prev, dr);
    }
    const int sig2 = NSTRIP - 1 - sig;   // flipped strip index == this block's own rows
    {
        float* Lr = Llast2 + ((size_t)s * NSTRIP + sig2) * WDIM + c0;
        *(float4*)Lr       = make_float4(prev[0], prev[1], prev[2], prev[3]);
        *(float4*)(Lr + 4) = make_float4(prev[4], prev[5], prev[6], prev[7]);
        store_minmax(prev, mm2, s * NSTRIP + sig2, lane);
    }
    if (lane == 0) release_add(&cnt[NSAMP + s]);

    // ---------------- phase 3: exact pass-2 rows (dr from own LDS) + fused loss -> sacc
    acquire_wait(&cnt[NSAMP + s], NSTRIP);
    if (sig2 == 0) {
#pragma unroll
        for (int i = 0; i < 8; ++i) prev[i] = INF_W;
    } else {
        inline_bounds(Llast2 + (size_t)s * NSTRIP * WDIM, sig2, jc, c0, prev,
                      mm2, s * NSTRIP, lane);
    }
    const size_t sb = (size_t)s * NPIX;
    float mx = 0.f, facc = 0.f, s1 = 0.f, s2 = 0.f, iacc = 0.f, pacc = 0.f;
#pragma unroll
    for (int t = 0; t < TST; ++t) {
        const int pr = R0 + (TST - 1) - t;        // == HDIM-1-(sig2*TST+t), own strip rows
        float4 a  = *(const float4*)&lds[TST - 1 - t][504 - c0];
        float4 b4 = *(const float4*)&lds[TST - 1 - t][508 - c0];
        float dr[8];
        dr[7]=a.x;  dr[6]=a.y;  dr[5]=a.z;  dr[4]=a.w;
        dr[3]=b4.x; dr[2]=b4.y; dr[1]=b4.z; dr[0]=b4.w;
        const size_t rbase = sb + (size_t)pr * WDIM + (WDIM - 8 - c0);
        float4 xa = *(const float4*)(pred + rbase);
        float4 xb = *(const float4*)(pred + rbase + 4);
        float px[8];
        px[7]=xa.x; px[6]=xa.y; px[5]=xa.z; px[4]=xa.w;
        px[3]=xb.x; px[2]=xb.y; px[1]=xb.z; px[0]=xb.w;
        // target bits for reversed columns: col 511-c0-i lives in lane 63-lane, bit 7-i
        int sh = __shfl((int)((rawbgp >> (8 * (TST - 1 - t))) & 0xFFu), 63 - lane);
        row_step(jc, prev, dr);
#pragma unroll
        for (int i = 0; i < 8; ++i) {
            float x = px[i];
            float dd = prev[i];
            float e = __expf(-fabsf(x));
            float inv = 1.f / (1.f + e);
            float pr_ = (x >= 0.f) ? inv : (1.f - inv);   // sigmoid(x)
            float L = __logf(1.f + e);                    // softplus(-|x|)
            bool t1 = ((sh >> (7 - i)) & 1) == 0;         // fg pixel
            float fo = t1 ? 0.25f * (1.f - pr_) * (1.f - pr_) * (fmaxf(-x, 0.f) + L)
                          : 0.75f * pr_ * pr_ * (fmaxf(x, 0.f) + L);
            facc += fo;
            float base = t1 ? (1.f - pr_) : pr_;
            s1 += base;
            s2 += base * dd;
            float tf = t1 ? 1.f : 0.f;
            iacc += tf * pr_;
            pacc += pr_ + tf;
            mx = fmaxf(mx, dd);
        }
    }
#pragma unroll
    for (int off = 32; off > 0; off >>= 1) {
        facc += __shfl_xor(facc, off);
        s1   += __shfl_xor(s1, off);
        s2   += __shfl_xor(s2, off);
        iacc += __shfl_xor(iacc, off);
        pacc += __shfl_xor(pacc, off);
        mx    = fmaxf(mx, __shfl_xor(mx, off));
    }
    if (lane == 0) {
        const int idx = s * NSTRIP + sig2;
        sacc[0 * NBLK + idx] = s1;
        sacc[1 * NBLK + idx] = s2;
        sacc[2 * NBLK + idx] = iacc;
        sacc[3 * NBLK + idx] = pacc;
        sacc[4 * NBLK + idx] = mx;
        sacc[5 * NBLK + idx] = facc;
    }
    if (lane == 0) release_add(&cnt[2 * NSAMP]);

    // ---------------- phase 4: final reduction in block 0 only
    if (blockIdx.x != 0) return;
    acquire_wait(&cnt[2 * NSAMP], NBLK);
    float fsum = 0.f, bsum = 0.f, dsum = 0.f, isum = 0.f;
    for (int ss = 0; ss < NSAMP; ++ss) {
        int i0 = ss * NSTRIP + lane, i1 = i0 + 64;
        float t1 = sacc[0 * NBLK + i0] + sacc[0 * NBLK + i1];
        float t2 = sacc[1 * NBLK + i0] + sacc[1 * NBLK + i1];
        float ia = sacc[2 * NBLK + i0] + sacc[2 * NBLK + i1];
        float pa = sacc[3 * NBLK + i0] + sacc[3 * NBLK + i1];
        float mxs = fmaxf(sacc[4 * NBLK + i0], sacc[4 * NBLK + i1]);
        float fa = sacc[5 * NBLK + i0] + sacc[5 * NBLK + i1];
        int   vv = blkflags[i0] | blkflags[i1];
#pragma unroll
        for (int off = 32; off > 0; off >>= 1) {
            t1 += __shfl_xor(t1, off);
            t2 += __shfl_xor(t2, off);
            ia += __shfl_xor(ia, off);
            pa += __shfl_xor(pa, off);
            fa += __shfl_xor(fa, off);
            mxs = fmaxf(mxs, __shfl_xor(mxs, off));
            vv |= __shfl_xor(vv, off);
        }
        bool hasb = (vv & 3) == 3;     // boundary nonempty (has_fg && has_bg)
        fsum += fa;
        float distsum = hasb ? ((mxs > 0.f) ? t2 / fmaxf(mxs, 1e-12f) : 0.f) : t1;
        bsum += t1 + distsum;
        dsum += (2.f * ia + 1e-6f) / (pa + 1e-6f);
        isum += (ia + 1e-6f) / (pa - ia + 1e-6f);
    }
    if (lane == 0) {
        float focal = fsum / NTOT_F;
        float bnd   = bsum / NTOT_F;
        float dice = 1.f - dsum / 16.f;
        float iou  = 1.f - isum / 16.f;
        float l0 = lv[0], l1 = lv[1], l2 = lv[2], l3 = lv[3];
        float total = expf(-l0) * focal + l0 + expf(-l1) * dice + l1
                    + expf(-l2) * bnd  + l2 + expf(-l3) * iou  + l3;
        out[0] = total; out[1] = focal; out[2] = dice; out[3] = bnd; out[4] = iou;
    }
}

extern "C" void kernel_launch(void* const* d_in, const int* in_sizes, int n_in,
                              void* d_out, int out_size, void* d_ws, size_t ws_size,
                              hipStream_t stream) {
    const float* pred = (const float*)d_in[0];
    const int*   tg   = (const int*)d_in[1];
    const float* lv   = (const float*)d_in[2];
    float* out = (float*)d_out;
    char* ws = (char*)d_ws;
    int*   cnt      = (int*)(ws + OFF_CNT);
    int*   blkflags = (int*)(ws + OFF_FLAGS);
    float* sacc     = (float*)(ws + OFF_SACC);
    float* mm1      = (float*)(ws + OFF_MM1);
    float* mm2      = (float*)(ws + OFF_MM2);
    float* Llast    = (float*)(ws + OFF_LLAST);
    float* Llast2   = (float*)(ws + OFF_LLAST2);

    // ws is poisoned between iterations -> sync counters must be zeroed each launch.
    // hipMemsetAsync is graph-capturable; single unconditional code path.
    hipMemsetAsync(cnt, 0, 256, stream);
    fused_kernel<<<NBLK, 64, 0, stream>>>(pred, tg, lv, out, Llast, mm1, blkflags,
                                          Llast2, mm2, sacc, cnt);
}

// Round 5
// 159.607 us; speedup vs baseline: 3.4710x; 3.0720x over previous
//
#include <hip/hip_runtime.h>
#include <math.h>

#define A_W 0.955f
#define B_W 1.3693f
#define INF_W 1e6f
#define HDIM 512
#define WDIM 512
#define NPIX (HDIM*WDIM)
#define NSAMP 16
#define NTOT_F 4194304.0f
#define TST 4        // strip height
#define NSTRIP 128   // strips per sample
#define NBLK (NSAMP*NSTRIP)        // 2048
#define STRIP_COST (4.0f * A_W)    // min cost to propagate a boundary through one strip

// ws layout (bytes):
//  [0,6144):        int cnt[3][16][32]  (one 128B line per (phase,sample) counter)
//  [8192,16384):    int blkflags[2048]  (per strip: bit0=has_fg, bit1=has_bg)
//  [16384,65536):   float sacc[6][2048]
//  [65536,81920):   float mm1[2][2048]  (min,max of Llast rows)
//  [81920,98304):   float mm2[2][2048]  (min,max of Llast2 rows)
//  [1MB,5MB):       float Llast[16][128][512]
//  [5MB,9MB):       float Llast2[16][128][512]
#define OFF_CNT    0
#define OFF_FLAGS  8192
#define OFF_SACC   16384
#define OFF_MM1    65536
#define OFF_MM2    81920
#define OFF_LLAST  (1u<<20)
#define OFF_LLAST2 (5u<<20)

// ---- fence-free cross-block data movement --------------------------------------
// gfx950 XCD L2s are non-coherent; agent-scope ACQ/REL atomics compile to whole-L2
// writeback/invalidate ops (buffer_wbl2/buffer_inv). Round-4 post-mortem: 6144
// releases + 6144 acquires of that form left the kernel 97% idle at ~440us with
// ~zero traffic — the cache-maintenance ops were the floor. Instead, ALL cross-block
// payload uses RELAXED agent-scope loads/stores (per-op sc0/sc1 bits: write-through
// to / read-from MALL, no L2 flush), and counters use RELAXED RMW preceded by an
// explicit s_waitcnt vmcnt(0) (drains this wave's write-through stores to MALL
// before the count bump). Readers observe the counter (MALL), then read payload
// from MALL — data is final there before the counter flips, so no fences needed.
__device__ __forceinline__ void st_wti(int* p, int v) {
    __hip_atomic_store(p, v, __ATOMIC_RELAXED, __HIP_MEMORY_SCOPE_AGENT);
}
__device__ __forceinline__ int ld_bpi(const int* p) {
    return __hip_atomic_load((int*)p, __ATOMIC_RELAXED, __HIP_MEMORY_SCOPE_AGENT);
}
__device__ __forceinline__ void st_wt(float* p, float v) {
    st_wti((int*)p, __float_as_int(v));
}
__device__ __forceinline__ float ld_bp(const float* p) {
    return __int_as_float(ld_bpi((const int*)p));
}

// lane-0-only call; the s_waitcnt is wave-level so it covers all 64 lanes' stores.
__device__ __forceinline__ void fence_release_add(int* p) {
    asm volatile("s_waitcnt vmcnt(0)" ::: "memory");
    __hip_atomic_fetch_add(p, 1, __ATOMIC_RELAXED, __HIP_MEMORY_SCOPE_AGENT);
}
__device__ __forceinline__ void spin_wait(int* p, int target) {
    while (__hip_atomic_load(p, __ATOMIC_RELAXED, __HIP_MEMORY_SCOPE_AGENT) < target)
        __builtin_amdgcn_s_sleep(8);
    asm volatile("" ::: "memory");   // no payload reads hoisted above the spin
}

// DPP move with INF fill (floats).
template<int CTRL, int RMASK>
__device__ __forceinline__ float dpp_mov_inf(float x) {
    return __int_as_float(__builtin_amdgcn_update_dpp(
        __float_as_int(INF_W), __float_as_int(x), CTRL, RMASK, 0xF, false));
}
template<int CTRL>
__device__ __forceinline__ int dpp_mov0_i(int x) {
    return __builtin_amdgcn_update_dpp(0, x, CTRL, 0xF, 0xF, true);
}

__device__ __forceinline__ float wave_prefix_min_incl(float t) {
    t = fminf(t, dpp_mov_inf<0x111,0xF>(t));
    t = fminf(t, dpp_mov_inf<0x112,0xF>(t));
    t = fminf(t, dpp_mov_inf<0x114,0xF>(t));
    t = fminf(t, dpp_mov_inf<0x118,0xF>(t));
    t = fminf(t, dpp_mov_inf<0x142,0xA>(t));
    t = fminf(t, dpp_mov_inf<0x143,0xC>(t));
    return t;
}

__device__ __forceinline__ void cummin_row(const float* jc, float* v) {
    float g[8];
#pragma unroll
    for (int i = 0; i < 8; ++i) g[i] = v[i] - jc[i];
    float c1[8];
    c1[0] = g[0];
#pragma unroll
    for (int i = 1; i < 8; ++i) c1[i] = fminf(g[i], g[i-1]);
    float c2[8];
    c2[0] = c1[0]; c2[1] = c1[1];
#pragma unroll
    for (int i = 2; i < 8; ++i) c2[i] = fminf(c1[i], c1[i-2]);
    float cj[8];
    cj[0] = c2[0]; cj[1] = c2[1]; cj[2] = c2[2]; cj[3] = c2[3];
#pragma unroll
    for (int i = 4; i < 8; ++i) cj[i] = fminf(c2[i], c2[i-4]);
    float t  = wave_prefix_min_incl(cj[7]);
    float ex = dpp_mov_inf<0x138,0xF>(t);
#pragma unroll
    for (int i = 0; i < 8; ++i) v[i] = jc[i] + fminf(cj[i], ex);
}

__device__ __forceinline__ void row_step(const float* jc, float* prev, const float* drow) {
    float lIn = dpp_mov_inf<0x138,0xF>(prev[7]);
    float rIn = dpp_mov_inf<0x130,0xF>(prev[0]);
    float m[8];
#pragma unroll
    for (int i = 0; i < 8; ++i) {
        float up = prev[i] + A_W;
        float ul = ((i == 0) ? lIn : prev[i-1]) + B_W;
        float ur = ((i == 7) ? rIn : prev[i+1]) + B_W;
        m[i] = fminf(fminf(drow[i], up), fminf(ul, ur));
    }
    cummin_row(jc, m);
#pragma unroll
    for (int i = 0; i < 8; ++i) prev[i] = m[i];
}

// 4 fused T3 steps (exact, INF outside grid). T3^4 == one call (TST==4).
__device__ __forceinline__ void t3x4(float* b) {
    float e[16];
#pragma unroll
    for (int k = 0; k < 4; ++k) e[k]    = dpp_mov_inf<0x138,0xF>(b[4+k]);
#pragma unroll
    for (int k = 0; k < 8; ++k) e[4+k]  = b[k];
#pragma unroll
    for (int k = 0; k < 4; ++k) e[12+k] = dpp_mov_inf<0x130,0xF>(b[k]);
    const float w0 = 4.f*A_W, w1 = 3.f*A_W + B_W, w2 = 2.f*A_W + 2.f*B_W;
    const float w3 = A_W + 3.f*B_W, w4 = 4.f*B_W;
#pragma unroll
    for (int i = 0; i < 8; ++i) {
        float m = e[i+4] + w0;
        m = fminf(m, fminf(e[i+3], e[i+5]) + w1);
        m = fminf(m, fminf(e[i+2], e[i+6]) + w2);
        m = fminf(m, fminf(e[i+1], e[i+7]) + w3);
        m = fminf(m, fminf(e[i+0], e[i+8]) + w4);
        b[i] = m;
    }
}

struct RowBits { int efg; int ebg; int rawbg; };

__device__ __forceinline__ RowBits make_rowbits(uint4 a, uint4 b) {
    int fg = ((a.x!=0u)?1:0) | ((a.y!=0u)?2:0) | ((a.z!=0u)?4:0) | ((a.w!=0u)?8:0)
           | ((b.x!=0u)?16:0) | ((b.y!=0u)?32:0) | ((b.z!=0u)?64:0) | ((b.w!=0u)?128:0);
    int bg = (~fg) & 0xFF;
    int lf = dpp_mov0_i<0x138>(fg), rf = dpp_mov0_i<0x130>(fg);
    int lb = dpp_mov0_i<0x138>(bg), rb = dpp_mov0_i<0x130>(bg);
    RowBits r;
    r.efg = (fg | (fg<<1) | (fg>>1) | ((lf>>7)&1) | ((rf&1)<<7)) & 0xFF;
    r.ebg = (bg | (bg<<1) | (bg>>1) | ((lb>>7)&1) | ((rb&1)<<7)) & 0xFF;
    r.rawbg = bg;
    return r;
}

__device__ __forceinline__ RowBits loadrow_bits(const int* tgb, int rr, int c0) {
    if (rr < 0 || rr >= HDIM) { RowBits z; z.efg = 0; z.ebg = 0; z.rawbg = 0; return z; }
    const uint4* p = (const uint4*)(tgb + (size_t)rr * WDIM + c0);
    return make_rowbits(p[0], p[1]);
}

// store min/max of an L row (prev[8] across wave) into mm arrays (write-through)
__device__ __forceinline__ void store_minmax(const float* prev, float* __restrict__ mm,
                                             int idx, int lane) {
    float mn = prev[0], mx = prev[0];
#pragma unroll
    for (int i = 1; i < 8; ++i) { mn = fminf(mn, prev[i]); mx = fmaxf(mx, prev[i]); }
#pragma unroll
    for (int off = 32; off > 0; off >>= 1) {
        mn = fminf(mn, __shfl_xor(mn, off));
        mx = fmaxf(mx, __shfl_xor(mx, off));
    }
    if (lane == 0) { st_wt(&mm[idx], mn); st_wt(&mm[NBLK + idx], mx); }
}

// Inline exact boundary with dominance pruning over up to 127 strips (two 64-wide
// ballot segments). Strip k skippable when minL[k] + STRIP_COST*(n-1-k) > maxL[n-1].
// All Lb/mm reads are MALL-bypass (written by other blocks).
__device__ __forceinline__ void inline_bounds(const float* __restrict__ Lb, int n,
                                              const float* jc, int c0, float* prev,
                                              const float* __restrict__ mm, int base,
                                              int lane) {
    float ub = ld_bp(&mm[NBLK + base + (n - 1)]);        // maxL[n-1]
    int k0 = n - 1;
    {
        int k = lane;
        float mv = (k < n) ? ld_bp(&mm[base + k]) : 0.f;
        bool c = (k < n) && (mv + STRIP_COST * (float)(n - 1 - k) <= ub);
        unsigned long long m0 = __ballot((int)c);
        if (m0 != 0ull) {
            k0 = __ffsll((long long)m0) - 1;
        } else if (n > 64) {
            k = 64 + lane;
            float mv1 = (k < n) ? ld_bp(&mm[base + k]) : 0.f;
            bool c1 = (k < n) && (mv1 + STRIP_COST * (float)(n - 1 - k) <= ub);
            unsigned long long m1 = __ballot((int)c1);
            if (m1 != 0ull) k0 = 64 + __ffsll((long long)m1) - 1;
        }
    }

    float b[8];
    const float* Lr = Lb + (size_t)k0 * WDIM + c0;
#pragma unroll
    for (int i = 0; i < 8; ++i) b[i] = ld_bp(&Lr[i]);
    for (int sg = k0 + 1; sg < n; ++sg) {
        const float* Ls = Lb + (size_t)sg * WDIM + c0;
        float m0[8];
#pragma unroll
        for (int i = 0; i < 8; ++i) m0[i] = ld_bp(&Ls[i]);
        t3x4(b);                                 // T3^4 exact (TST==4)
        cummin_row(jc, b);
#pragma unroll
        for (int i = 0; i < 8; ++i) b[i] = fminf(b[i], m0[i]);
    }
#pragma unroll
    for (int i = 0; i < 8; ++i) prev[i] = b[i];
}

// =====================================================================================
// Fused kernel: all 3 strip phases + final reduce in ONE dispatch.
// Co-residency by construction: __launch_bounds__(64,2) caps VGPR at 256; any
// VGPR<=256 gives >=2 waves/SIMD -> >=8 single-wave blocks/CU -> >=2048 slots =
// grid size (LDS 8KB -> 20/CU, not binding) => spins cannot deadlock.
// (64,4) is forbidden: VGPR squeezed to 64 and spilled ~90MB scratch (round 3).
// =====================================================================================
__global__ __launch_bounds__(64, 2) void fused_kernel(
        const float* __restrict__ pred, const int* __restrict__ tg,
        const float* __restrict__ lv, float* __restrict__ out,
        float* __restrict__ Llast, float* __restrict__ mm1, int* __restrict__ blkflags,
        float* __restrict__ Llast2, float* __restrict__ mm2, float* __restrict__ sacc,
        int* cnt) {
    const int s = blockIdx.x >> 7, sig = blockIdx.x & 127;
    const int lane = threadIdx.x;
    const int c0 = lane * 8;
    const int* tgb = tg + (size_t)s * NPIX;
    const int R0 = sig * TST;
    // padded counters: one 128B line per (phase, sample)
    int* c1 = cnt + 0 * 512 + s * 32;
    int* c2 = cnt + 1 * 512 + s * 32;
    int* c3 = cnt + 2 * 512 + s * 32;
    float jc[8];
#pragma unroll
    for (int i = 0; i < 8; ++i) jc[i] = A_W * (float)(c0 + i);

    __shared__ float lds[TST][WDIM];   // 8 KB; single-wave block

    // ---------------- phase 1: local strip scan (INF incoming) -> Llast/mm1/flags
    unsigned int smaskp = 0u, rawbgp = 0u;   // byte t = row t's 8-bit masks
    RowBits rA = loadrow_bits(tgb, R0 - 1, c0);
    RowBits rB = loadrow_bits(tgb, R0, c0);
    float prev[8];
#pragma unroll
    for (int i = 0; i < 8; ++i) prev[i] = INF_W;
    int fgor = 0, bgor = 0;
#pragma unroll
    for (int t = 0; t < TST; ++t) {
        RowBits rC = loadrow_bits(tgb, R0 + t + 1, c0);
        fgor |= (~rB.rawbg) & 0xFF;
        bgor |= rB.rawbg;
        int smask = (rA.efg | rB.efg | rC.efg) & (rA.ebg | rB.ebg | rC.ebg);
        smaskp |= ((unsigned int)smask) << (8 * t);
        rawbgp |= ((unsigned int)rB.rawbg) << (8 * t);
        float dr[8];
#pragma unroll
        for (int i = 0; i < 8; ++i) dr[i] = ((smask >> i) & 1) ? 0.f : INF_W;
        row_step(jc, prev, dr);
        rA = rB; rB = rC;
    }
    {
        float* Lr = Llast + ((size_t)s * NSTRIP + sig) * WDIM + c0;
#pragma unroll
        for (int i = 0; i < 8; ++i) st_wt(&Lr[i], prev[i]);
        store_minmax(prev, mm1, s * NSTRIP + sig, lane);
        int wf = __any(fgor != 0) ? 1 : 0;
        int wb = __any(bgor != 0) ? 2 : 0;
        if (lane == 0) st_wti(&blkflags[blockIdx.x], wf | wb);
    }
    if (lane == 0) fence_release_add(c1);

    // ---------------- phase 2: exact pass-1 rows -> LDS; flipped local scan -> Llast2/mm2
    spin_wait(c1, NSTRIP);
    if (sig == 0) {
#pragma unroll
        for (int i = 0; i < 8; ++i) prev[i] = INF_W;
    } else {
        inline_bounds(Llast + (size_t)s * NSTRIP * WDIM, sig, jc, c0, prev,
                      mm1, s * NSTRIP, lane);
    }
#pragma unroll
    for (int t = 0; t < TST; ++t) {
        unsigned int sm = (smaskp >> (8 * t)) & 0xFFu;
        float dr[8];
#pragma unroll
        for (int i = 0; i < 8; ++i) dr[i] = ((sm >> i) & 1u) ? 0.f : INF_W;
        row_step(jc, prev, dr);
        *(float4*)&lds[t][c0]     = make_float4(prev[0], prev[1], prev[2], prev[3]);
        *(float4*)&lds[t][c0 + 4] = make_float4(prev[4], prev[5], prev[6], prev[7]);
    }
    __syncthreads();
    // flipped (pass-2) local scan over this strip, INF incoming
#pragma unroll
    for (int i = 0; i < 8; ++i) prev[i] = INF_W;
#pragma unroll
    for (int t2 = 0; t2 < TST; ++t2) {
        float4 a = *(const float4*)&lds[TST - 1 - t2][504 - c0];
        float4 q = *(const float4*)&lds[TST - 1 - t2][508 - c0];
        float dr[8];
        dr[7]=a.x; dr[6]=a.y; dr[5]=a.z; dr[4]=a.w;
        dr[3]=q.x; dr[2]=q.y; dr[1]=q.z; dr[0]=q.w;
        row_step(jc, prev, dr);
    }
    const int sig2 = NSTRIP - 1 - sig;   // flipped strip index == this block's own rows
    {
        float* Lr = Llast2 + ((size_t)s * NSTRIP + sig2) * WDIM + c0;
#pragma unroll
        for (int i = 0; i < 8; ++i) st_wt(&Lr[i], prev[i]);
        store_minmax(prev, mm2, s * NSTRIP + sig2, lane);
    }
    if (lane == 0) fence_release_add(c2);

    // ---------------- phase 3: exact pass-2 rows (dr from own LDS) + fused loss -> sacc
    spin_wait(c2, NSTRIP);
    if (sig2 == 0) {
#pragma unroll
        for (int i = 0; i < 8; ++i) prev[i] = INF_W;
    } else {
        inline_bounds(Llast2 + (size_t)s * NSTRIP * WDIM, sig2, jc, c0, prev,
                      mm2, s * NSTRIP, lane);
    }
    const size_t sb = (size_t)s * NPIX;
    float mx = 0.f, facc = 0.f, s1 = 0.f, s2 = 0.f, iacc = 0.f, pacc = 0.f;
#pragma unroll
    for (int t = 0; t < TST; ++t) {
        const int pr = R0 + (TST - 1) - t;        // == HDIM-1-(sig2*TST+t), own strip rows
        float4 a  = *(const float4*)&lds[TST - 1 - t][504 - c0];
        float4 b4 = *(const float4*)&lds[TST - 1 - t][508 - c0];
        float dr[8];
        dr[7]=a.x;  dr[6]=a.y;  dr[5]=a.z;  dr[4]=a.w;
        dr[3]=b4.x; dr[2]=b4.y; dr[1]=b4.z; dr[0]=b4.w;
        const size_t rbase = sb + (size_t)pr * WDIM + (WDIM - 8 - c0);
        float4 xa = *(const float4*)(pred + rbase);
        float4 xb = *(const float4*)(pred + rbase + 4);
        float px[8];
        px[7]=xa.x; px[6]=xa.y; px[5]=xa.z; px[4]=xa.w;
        px[3]=xb.x; px[2]=xb.y; px[1]=xb.z; px[0]=xb.w;
        // target bits for reversed columns: col 511-c0-i lives in lane 63-lane, bit 7-i
        int sh = __shfl((int)((rawbgp >> (8 * (TST - 1 - t))) & 0xFFu), 63 - lane);
        row_step(jc, prev, dr);
#pragma unroll
        for (int i = 0; i < 8; ++i) {
            float x = px[i];
            float dd = prev[i];
            float e = __expf(-fabsf(x));
            float inv = 1.f / (1.f + e);
            float pr_ = (x >= 0.f) ? inv : (1.f - inv);   // sigmoid(x)
            float L = __logf(1.f + e);                    // softplus(-|x|)
            bool t1 = ((sh >> (7 - i)) & 1) == 0;         // fg pixel
            float fo = t1 ? 0.25f * (1.f - pr_) * (1.f - pr_) * (fmaxf(-x, 0.f) + L)
                          : 0.75f * pr_ * pr_ * (fmaxf(x, 0.f) + L);
            facc += fo;
            float base = t1 ? (1.f - pr_) : pr_;
            s1 += base;
            s2 += base * dd;
            float tf = t1 ? 1.f : 0.f;
            iacc += tf * pr_;
            pacc += pr_ + tf;
            mx = fmaxf(mx, dd);
        }
    }
#pragma unroll
    for (int off = 32; off > 0; off >>= 1) {
        facc += __shfl_xor(facc, off);
        s1   += __shfl_xor(s1, off);
        s2   += __shfl_xor(s2, off);
        iacc += __shfl_xor(iacc, off);
        pacc += __shfl_xor(pacc, off);
        mx    = fmaxf(mx, __shfl_xor(mx, off));
    }
    if (lane == 0) {
        const int idx = s * NSTRIP + sig2;
        st_wt(&sacc[0 * NBLK + idx], s1);
        st_wt(&sacc[1 * NBLK + idx], s2);
        st_wt(&sacc[2 * NBLK + idx], iacc);
        st_wt(&sacc[3 * NBLK + idx], pacc);
        st_wt(&sacc[4 * NBLK + idx], mx);
        st_wt(&sacc[5 * NBLK + idx], facc);
        fence_release_add(c3);
    }

    // ---------------- phase 4: final reduction in block 0 only
    if (blockIdx.x != 0) return;
    for (int ss = 0; ss < NSAMP; ++ss) spin_wait(cnt + 2 * 512 + ss * 32, NSTRIP);
    float fsum = 0.f, bsum = 0.f, dsum = 0.f, isum = 0.f;
    for (int ss = 0; ss < NSAMP; ++ss) {
        int i0 = ss * NSTRIP + lane, i1 = i0 + 64;
        float t1 = ld_bp(&sacc[0 * NBLK + i0]) + ld_bp(&sacc[0 * NBLK + i1]);
        float t2 = ld_bp(&sacc[1 * NBLK + i0]) + ld_bp(&sacc[1 * NBLK + i1]);
        float ia = ld_bp(&sacc[2 * NBLK + i0]) + ld_bp(&sacc[2 * NBLK + i1]);
        float pa = ld_bp(&sacc[3 * NBLK + i0]) + ld_bp(&sacc[3 * NBLK + i1]);
        float mxs = fmaxf(ld_bp(&sacc[4 * NBLK + i0]), ld_bp(&sacc[4 * NBLK + i1]));
        float fa = ld_bp(&sacc[5 * NBLK + i0]) + ld_bp(&sacc[5 * NBLK + i1]);
        int   vv = ld_bpi(&blkflags[i0]) | ld_bpi(&blkflags[i1]);
#pragma unroll
        for (int off = 32; off > 0; off >>= 1) {
            t1 += __shfl_xor(t1, off);
            t2 += __shfl_xor(t2, off);
            ia += __shfl_xor(ia, off);
            pa += __shfl_xor(pa, off);
            fa += __shfl_xor(fa, off);
            mxs = fmaxf(mxs, __shfl_xor(mxs, off));
            vv |= __shfl_xor(vv, off);
        }
        bool hasb = (vv & 3) == 3;     // boundary nonempty (has_fg && has_bg)
        fsum += fa;
        float distsum = hasb ? ((mxs > 0.f) ? t2 / fmaxf(mxs, 1e-12f) : 0.f) : t1;
        bsum += t1 + distsum;
        dsum += (2.f * ia + 1e-6f) / (pa + 1e-6f);
        isum += (ia + 1e-6f) / (pa - ia + 1e-6f);
    }
    if (lane == 0) {
        float focal = fsum / NTOT_F;
        float bnd   = bsum / NTOT_F;
        float dice = 1.f - dsum / 16.f;
        float iou  = 1.f - isum / 16.f;
        float l0 = lv[0], l1 = lv[1], l2 = lv[2], l3 = lv[3];
        float total = expf(-l0) * focal + l0 + expf(-l1) * dice + l1
                    + expf(-l2) * bnd  + l2 + expf(-l3) * iou  + l3;
        out[0] = total; out[1] = focal; out[2] = dice; out[3] = bnd; out[4] = iou;
    }
}

extern "C" void kernel_launch(void* const* d_in, const int* in_sizes, int n_in,
                              void* d_out, int out_size, void* d_ws, size_t ws_size,
                              hipStream_t stream) {
    const float* pred = (const float*)d_in[0];
    const int*   tg   = (const int*)d_in[1];
    const float* lv   = (const float*)d_in[2];
    float* out = (float*)d_out;
    char* ws = (char*)d_ws;
    int*   cnt      = (int*)(ws + OFF_CNT);
    int*   blkflags = (int*)(ws + OFF_FLAGS);
    float* sacc     = (float*)(ws + OFF_SACC);
    float* mm1      = (float*)(ws + OFF_MM1);
    float* mm2      = (float*)(ws + OFF_MM2);
    float* Llast    = (float*)(ws + OFF_LLAST);
    float* Llast2   = (float*)(ws + OFF_LLAST2);

    // ws is poisoned between iterations -> sync counters must be zeroed each launch.
    hipMemsetAsync(cnt, 0, 6144, stream);
    fused_kernel<<<NBLK, 64, 0, stream>>>(pred, tg, lv, out, Llast, mm1, blkflags,
                                          Llast2, mm2, sacc, cnt);
}

// Round 6
// 142.905 us; speedup vs baseline: 3.8766x; 1.1169x over previous
//
#include <hip/hip_runtime.h>
#include <math.h>

#define A_W 0.955f
#define B_W 1.3693f
#define INF_W 1e6f
#define HDIM 512
#define WDIM 512
#define NPIX (HDIM*WDIM)
#define NSAMP 16
#define NTOT_F 4194304.0f
#define TST 4        // strip height
#define NSTRIP 128   // strips per sample
#define NBLK (NSAMP*NSTRIP)        // 2048
#define STRIP_COST (4.0f * A_W)    // min cost to propagate a boundary through one strip

// ws layout (bytes):
//  [0,6144):        int cnt[3][16][32]  (one 128B line per (phase,sample) counter)
//  [8192,16384):    int blkflags[2048]  (per strip: bit0=has_fg, bit1=has_bg)
//  [16384,65536):   float sacc[6][2048]
//  [65536,81920):   float mm1[2][2048]  (min,max of Llast rows)
//  [81920,98304):   float mm2[2][2048]  (min,max of Llast2 rows)
//  [1MB,5MB):       float Llast[16][128][512]
//  [5MB,9MB):       float Llast2[16][128][512]
#define OFF_CNT    0
#define OFF_FLAGS  8192
#define OFF_SACC   16384
#define OFF_MM1    65536
#define OFF_MM2    81920
#define OFF_LLAST  (1u<<20)
#define OFF_LLAST2 (5u<<20)

typedef float f32x4 __attribute__((ext_vector_type(4)));

// ---- fence-free cross-block data movement --------------------------------------
// gfx950 XCD L2s are non-coherent; agent-scope ACQ/REL atomics compile to whole-L2
// writeback/invalidate (round-4: ~420us floor from 12K such ops). Scheme (round-5,
// verified correct): payload moves with L1+L2-BYPASS accesses (data lands in / is
// read from MALL, which is common to all XCDs); producers drain with s_waitcnt
// vmcnt(0) then bump a RELAXED counter; consumers spin RELAXED. Dispatch-boundary
// implicit cache flush covers pre-kernel state (why plain cached tg/pred loads and
// the poisoned ws are safe).
// Round-5 post-mortem: PER-DWORD bypass atomics gave 8.1x write amplification
// (WRITE_SIZE 66.4MB vs 8.2MB payload; 8B used per 64B line, no L2 merge by
// design). Fix: dwordx4 bypass ops via inline asm (full-line granularity).
__device__ __forceinline__ void st_wti(int* p, int v) {
    __hip_atomic_store(p, v, __ATOMIC_RELAXED, __HIP_MEMORY_SCOPE_AGENT);
}
__device__ __forceinline__ int ld_bpi(const int* p) {
    return __hip_atomic_load((int*)p, __ATOMIC_RELAXED, __HIP_MEMORY_SCOPE_AGENT);
}
__device__ __forceinline__ void st_wt(float* p, float v) {
    st_wti((int*)p, __float_as_int(v));
}
__device__ __forceinline__ float ld_bp(const float* p) {
    return __int_as_float(ld_bpi((const int*)p));
}
// 16B-wide L1+L2-bypass ops. Results of ld_bp4 may ONLY be read after vm_wait0()
// (compiler does not track asm vmem; rule: asm waitcnt + sched_barrier before use).
__device__ __forceinline__ f32x4 ld_bp4(const float* p) {
    f32x4 r;
    asm volatile("global_load_dwordx4 %0, %1, off sc0 sc1"
                 : "=v"(r) : "v"(p) : "memory");
    return r;
}
__device__ __forceinline__ void st_wt4(float* p, f32x4 v) {
    asm volatile("global_store_dwordx4 %0, %1, off sc0 sc1"
                 :: "v"(p), "v"(v) : "memory");
}
__device__ __forceinline__ void vm_wait0() {
    asm volatile("s_waitcnt vmcnt(0)" ::: "memory");
    __builtin_amdgcn_sched_barrier(0);   // block reg-only hoisting past the wait
}

// lane-0-only call; the s_waitcnt is wave-level so it covers all 64 lanes' stores.
__device__ __forceinline__ void fence_release_add(int* p) {
    asm volatile("s_waitcnt vmcnt(0)" ::: "memory");
    __hip_atomic_fetch_add(p, 1, __ATOMIC_RELAXED, __HIP_MEMORY_SCOPE_AGENT);
}
__device__ __forceinline__ void spin_wait(int* p, int target) {
    while (__hip_atomic_load(p, __ATOMIC_RELAXED, __HIP_MEMORY_SCOPE_AGENT) < target)
        __builtin_amdgcn_s_sleep(8);
    asm volatile("" ::: "memory");   // no payload reads hoisted above the spin
}

// DPP move with INF fill (floats).
template<int CTRL, int RMASK>
__device__ __forceinline__ float dpp_mov_inf(float x) {
    return __int_as_float(__builtin_amdgcn_update_dpp(
        __float_as_int(INF_W), __float_as_int(x), CTRL, RMASK, 0xF, false));
}
template<int CTRL>
__device__ __forceinline__ int dpp_mov0_i(int x) {
    return __builtin_amdgcn_update_dpp(0, x, CTRL, 0xF, 0xF, true);
}

__device__ __forceinline__ float wave_prefix_min_incl(float t) {
    t = fminf(t, dpp_mov_inf<0x111,0xF>(t));
    t = fminf(t, dpp_mov_inf<0x112,0xF>(t));
    t = fminf(t, dpp_mov_inf<0x114,0xF>(t));
    t = fminf(t, dpp_mov_inf<0x118,0xF>(t));
    t = fminf(t, dpp_mov_inf<0x142,0xA>(t));
    t = fminf(t, dpp_mov_inf<0x143,0xC>(t));
    return t;
}

__device__ __forceinline__ void cummin_row(const float* jc, float* v) {
    float g[8];
#pragma unroll
    for (int i = 0; i < 8; ++i) g[i] = v[i] - jc[i];
    float c1[8];
    c1[0] = g[0];
#pragma unroll
    for (int i = 1; i < 8; ++i) c1[i] = fminf(g[i], g[i-1]);
    float c2[8];
    c2[0] = c1[0]; c2[1] = c1[1];
#pragma unroll
    for (int i = 2; i < 8; ++i) c2[i] = fminf(c1[i], c1[i-2]);
    float cj[8];
    cj[0] = c2[0]; cj[1] = c2[1]; cj[2] = c2[2]; cj[3] = c2[3];
#pragma unroll
    for (int i = 4; i < 8; ++i) cj[i] = fminf(c2[i], c2[i-4]);
    float t  = wave_prefix_min_incl(cj[7]);
    float ex = dpp_mov_inf<0x138,0xF>(t);
#pragma unroll
    for (int i = 0; i < 8; ++i) v[i] = jc[i] + fminf(cj[i], ex);
}

__device__ __forceinline__ void row_step(const float* jc, float* prev, const float* drow) {
    float lIn = dpp_mov_inf<0x138,0xF>(prev[7]);
    float rIn = dpp_mov_inf<0x130,0xF>(prev[0]);
    float m[8];
#pragma unroll
    for (int i = 0; i < 8; ++i) {
        float up = prev[i] + A_W;
        float ul = ((i == 0) ? lIn : prev[i-1]) + B_W;
        float ur = ((i == 7) ? rIn : prev[i+1]) + B_W;
        m[i] = fminf(fminf(drow[i], up), fminf(ul, ur));
    }
    cummin_row(jc, m);
#pragma unroll
    for (int i = 0; i < 8; ++i) prev[i] = m[i];
}

// 4 fused T3 steps (exact, INF outside grid). T3^4 == one call (TST==4).
__device__ __forceinline__ void t3x4(float* b) {
    float e[16];
#pragma unroll
    for (int k = 0; k < 4; ++k) e[k]    = dpp_mov_inf<0x138,0xF>(b[4+k]);
#pragma unroll
    for (int k = 0; k < 8; ++k) e[4+k]  = b[k];
#pragma unroll
    for (int k = 0; k < 4; ++k) e[12+k] = dpp_mov_inf<0x130,0xF>(b[k]);
    const float w0 = 4.f*A_W, w1 = 3.f*A_W + B_W, w2 = 2.f*A_W + 2.f*B_W;
    const float w3 = A_W + 3.f*B_W, w4 = 4.f*B_W;
#pragma unroll
    for (int i = 0; i < 8; ++i) {
        float m = e[i+4] + w0;
        m = fminf(m, fminf(e[i+3], e[i+5]) + w1);
        m = fminf(m, fminf(e[i+2], e[i+6]) + w2);
        m = fminf(m, fminf(e[i+1], e[i+7]) + w3);
        m = fminf(m, fminf(e[i+0], e[i+8]) + w4);
        b[i] = m;
    }
}

struct RowBits { int efg; int ebg; int rawbg; };

__device__ __forceinline__ RowBits make_rowbits(uint4 a, uint4 b) {
    int fg = ((a.x!=0u)?1:0) | ((a.y!=0u)?2:0) | ((a.z!=0u)?4:0) | ((a.w!=0u)?8:0)
           | ((b.x!=0u)?16:0) | ((b.y!=0u)?32:0) | ((b.z!=0u)?64:0) | ((b.w!=0u)?128:0);
    int bg = (~fg) & 0xFF;
    int lf = dpp_mov0_i<0x138>(fg), rf = dpp_mov0_i<0x130>(fg);
    int lb = dpp_mov0_i<0x138>(bg), rb = dpp_mov0_i<0x130>(bg);
    RowBits r;
    r.efg = (fg | (fg<<1) | (fg>>1) | ((lf>>7)&1) | ((rf&1)<<7)) & 0xFF;
    r.ebg = (bg | (bg<<1) | (bg>>1) | ((lb>>7)&1) | ((rb&1)<<7)) & 0xFF;
    r.rawbg = bg;
    return r;
}

__device__ __forceinline__ RowBits loadrow_bits(const int* tgb, int rr, int c0) {
    if (rr < 0 || rr >= HDIM) { RowBits z; z.efg = 0; z.ebg = 0; z.rawbg = 0; return z; }
    const uint4* p = (const uint4*)(tgb + (size_t)rr * WDIM + c0);
    return make_rowbits(p[0], p[1]);
}

// store min/max of an L row (prev[8] across wave) into mm arrays (bypass stores)
__device__ __forceinline__ void store_minmax(const float* prev, float* __restrict__ mm,
                                             int idx, int lane) {
    float mn = prev[0], mx = prev[0];
#pragma unroll
    for (int i = 1; i < 8; ++i) { mn = fminf(mn, prev[i]); mx = fmaxf(mx, prev[i]); }
#pragma unroll
    for (int off = 32; off > 0; off >>= 1) {
        mn = fminf(mn, __shfl_xor(mn, off));
        mx = fmaxf(mx, __shfl_xor(mx, off));
    }
    if (lane == 0) { st_wt(&mm[idx], mn); st_wt(&mm[NBLK + idx], mx); }
}

// Inline exact boundary with dominance pruning over up to 127 strips (two 64-wide
// ballot segments). Strip k skippable when minL[k] + STRIP_COST*(n-1-k) > maxL[n-1].
// L-row reads: 16B bypass loads issued BEFORE t3x4/cummin so MALL latency hides
// under ~60 VALU ops; results consumed only after vm_wait0().
__device__ __forceinline__ void inline_bounds(const float* __restrict__ Lb, int n,
                                              const float* jc, int c0, float* prev,
                                              const float* __restrict__ mm, int base,
                                              int lane) {
    float ub = ld_bp(&mm[NBLK + base + (n - 1)]);        // maxL[n-1]
    int k0 = n - 1;
    {
        int k = lane;
        float mv = (k < n) ? ld_bp(&mm[base + k]) : 0.f;
        bool c = (k < n) && (mv + STRIP_COST * (float)(n - 1 - k) <= ub);
        unsigned long long m0 = __ballot((int)c);
        if (m0 != 0ull) {
            k0 = __ffsll((long long)m0) - 1;
        } else if (n > 64) {
            k = 64 + lane;
            float mv1 = (k < n) ? ld_bp(&mm[base + k]) : 0.f;
            bool c1 = (k < n) && (mv1 + STRIP_COST * (float)(n - 1 - k) <= ub);
            unsigned long long m1 = __ballot((int)c1);
            if (m1 != 0ull) k0 = 64 + __ffsll((long long)m1) - 1;
        }
    }

    float b[8];
    const float* Lr = Lb + (size_t)k0 * WDIM + c0;
    f32x4 l0 = ld_bp4(Lr);
    f32x4 l1 = ld_bp4(Lr + 4);
    vm_wait0();
#pragma unroll
    for (int i = 0; i < 4; ++i) { b[i] = l0[i]; b[4 + i] = l1[i]; }
    for (int sg = k0 + 1; sg < n; ++sg) {
        const float* Ls = Lb + (size_t)sg * WDIM + c0;
        f32x4 m0 = ld_bp4(Ls);
        f32x4 m1 = ld_bp4(Ls + 4);
        t3x4(b);                                 // T3^4 exact (TST==4)
        cummin_row(jc, b);
        vm_wait0();
#pragma unroll
        for (int i = 0; i < 4; ++i) {
            b[i]     = fminf(b[i],     m0[i]);
            b[4 + i] = fminf(b[4 + i], m1[i]);
        }
    }
#pragma unroll
    for (int i = 0; i < 8; ++i) prev[i] = b[i];
}

// =====================================================================================
// Fused kernel: all 3 strip phases + final reduce in ONE dispatch.
// Co-residency by construction: __launch_bounds__(64,2) caps VGPR at 256; any
// VGPR<=256 gives >=2 waves/SIMD -> >=8 single-wave blocks/CU -> >=2048 slots =
// grid size (LDS 8KB -> 20/CU, not binding) => spins cannot deadlock.
// (64,4) is forbidden: VGPR squeezed to 64 and spilled ~90MB scratch (round 3).
// =====================================================================================
__global__ __launch_bounds__(64, 2) void fused_kernel(
        const float* __restrict__ pred, const int* __restrict__ tg,
        const float* __restrict__ lv, float* __restrict__ out,
        float* __restrict__ Llast, float* __restrict__ mm1, int* __restrict__ blkflags,
        float* __restrict__ Llast2, float* __restrict__ mm2, float* __restrict__ sacc,
        int* cnt) {
    const int s = blockIdx.x >> 7, sig = blockIdx.x & 127;
    const int lane = threadIdx.x;
    const int c0 = lane * 8;
    const int* tgb = tg + (size_t)s * NPIX;
    const int R0 = sig * TST;
    // padded counters: one 128B line per (phase, sample)
    int* c1 = cnt + 0 * 512 + s * 32;
    int* c2 = cnt + 1 * 512 + s * 32;
    int* c3 = cnt + 2 * 512 + s * 32;
    float jc[8];
#pragma unroll
    for (int i = 0; i < 8; ++i) jc[i] = A_W * (float)(c0 + i);

    __shared__ float lds[TST][WDIM];   // 8 KB; single-wave block

    // ---------------- phase 1: local strip scan (INF incoming) -> Llast/mm1/flags
    unsigned int smaskp = 0u, rawbgp = 0u;   // byte t = row t's 8-bit masks
    RowBits rA = loadrow_bits(tgb, R0 - 1, c0);
    RowBits rB = loadrow_bits(tgb, R0, c0);
    float prev[8];
#pragma unroll
    for (int i = 0; i < 8; ++i) prev[i] = INF_W;
    int fgor = 0, bgor = 0;
#pragma unroll
    for (int t = 0; t < TST; ++t) {
        RowBits rC = loadrow_bits(tgb, R0 + t + 1, c0);
        fgor |= (~rB.rawbg) & 0xFF;
        bgor |= rB.rawbg;
        int smask = (rA.efg | rB.efg | rC.efg) & (rA.ebg | rB.ebg | rC.ebg);
        smaskp |= ((unsigned int)smask) << (8 * t);
        rawbgp |= ((unsigned int)rB.rawbg) << (8 * t);
        float dr[8];
#pragma unroll
        for (int i = 0; i < 8; ++i) dr[i] = ((smask >> i) & 1) ? 0.f : INF_W;
        row_step(jc, prev, dr);
        rA = rB; rB = rC;
    }
    {
        float* Lr = Llast + ((size_t)s * NSTRIP + sig) * WDIM + c0;
        f32x4 v0 = {prev[0], prev[1], prev[2], prev[3]};
        f32x4 v1 = {prev[4], prev[5], prev[6], prev[7]};
        st_wt4(Lr, v0);
        st_wt4(Lr + 4, v1);
        store_minmax(prev, mm1, s * NSTRIP + sig, lane);
        int wf = __any(fgor != 0) ? 1 : 0;
        int wb = __any(bgor != 0) ? 2 : 0;
        if (lane == 0) st_wti(&blkflags[blockIdx.x], wf | wb);
    }
    if (lane == 0) fence_release_add(c1);

    // ---------------- phase 2: exact pass-1 rows -> LDS; flipped local scan -> Llast2/mm2
    spin_wait(c1, NSTRIP);
    if (sig == 0) {
#pragma unroll
        for (int i = 0; i < 8; ++i) prev[i] = INF_W;
    } else {
        inline_bounds(Llast + (size_t)s * NSTRIP * WDIM, sig, jc, c0, prev,
                      mm1, s * NSTRIP, lane);
    }
#pragma unroll
    for (int t = 0; t < TST; ++t) {
        unsigned int sm = (smaskp >> (8 * t)) & 0xFFu;
        float dr[8];
#pragma unroll
        for (int i = 0; i < 8; ++i) dr[i] = ((sm >> i) & 1u) ? 0.f : INF_W;
        row_step(jc, prev, dr);
        *(float4*)&lds[t][c0]     = make_float4(prev[0], prev[1], prev[2], prev[3]);
        *(float4*)&lds[t][c0 + 4] = make_float4(prev[4], prev[5], prev[6], prev[7]);
    }
    __syncthreads();
    // flipped (pass-2) local scan over this strip, INF incoming
#pragma unroll
    for (int i = 0; i < 8; ++i) prev[i] = INF_W;
#pragma unroll
    for (int t2 = 0; t2 < TST; ++t2) {
        float4 a = *(const float4*)&lds[TST - 1 - t2][504 - c0];
        float4 q = *(const float4*)&lds[TST - 1 - t2][508 - c0];
        float dr[8];
        dr[7]=a.x; dr[6]=a.y; dr[5]=a.z; dr[4]=a.w;
        dr[3]=q.x; dr[2]=q.y; dr[1]=q.z; dr[0]=q.w;
        row_step(jc, prev, dr);
    }
    const int sig2 = NSTRIP - 1 - sig;   // flipped strip index == this block's own rows
    {
        float* Lr = Llast2 + ((size_t)s * NSTRIP + sig2) * WDIM + c0;
        f32x4 v0 = {prev[0], prev[1], prev[2], prev[3]};
        f32x4 v1 = {prev[4], prev[5], prev[6], prev[7]};
        st_wt4(Lr, v0);
        st_wt4(Lr + 4, v1);
        store_minmax(prev, mm2, s * NSTRIP + sig2, lane);
    }
    if (lane == 0) fence_release_add(c2);

    // ---------------- phase 3: exact pass-2 rows (dr from own LDS) + fused loss -> sacc
    spin_wait(c2, NSTRIP);
    if (sig2 == 0) {
#pragma unroll
        for (int i = 0; i < 8; ++i) prev[i] = INF_W;
    } else {
        inline_bounds(Llast2 + (size_t)s * NSTRIP * WDIM, sig2, jc, c0, prev,
                      mm2, s * NSTRIP, lane);
    }
    const size_t sb = (size_t)s * NPIX;
    float mx = 0.f, facc = 0.f, s1 = 0.f, s2 = 0.f, iacc = 0.f, pacc = 0.f;
#pragma unroll
    for (int t = 0; t < TST; ++t) {
        const int pr = R0 + (TST - 1) - t;        // == HDIM-1-(sig2*TST+t), own strip rows
        float4 a  = *(const float4*)&lds[TST - 1 - t][504 - c0];
        float4 b4 = *(const float4*)&lds[TST - 1 - t][508 - c0];
        float dr[8];
        dr[7]=a.x;  dr[6]=a.y;  dr[5]=a.z;  dr[4]=a.w;
        dr[3]=b4.x; dr[2]=b4.y; dr[1]=b4.z; dr[0]=b4.w;
        const size_t rbase = sb + (size_t)pr * WDIM + (WDIM - 8 - c0);
        float4 xa = *(const float4*)(pred + rbase);
        float4 xb = *(const float4*)(pred + rbase + 4);
        float px[8];
        px[7]=xa.x; px[6]=xa.y; px[5]=xa.z; px[4]=xa.w;
        px[3]=xb.x; px[2]=xb.y; px[1]=xb.z; px[0]=xb.w;
        // target bits for reversed columns: col 511-c0-i lives in lane 63-lane, bit 7-i
        int sh = __shfl((int)((rawbgp >> (8 * (TST - 1 - t))) & 0xFFu), 63 - lane);
        row_step(jc, prev, dr);
#pragma unroll
        for (int i = 0; i < 8; ++i) {
            float x = px[i];
            float dd = prev[i];
            float e = __expf(-fabsf(x));
            float inv = 1.f / (1.f + e);
            float pr_ = (x >= 0.f) ? inv : (1.f - inv);   // sigmoid(x)
            float L = __logf(1.f + e);                    // softplus(-|x|)
            bool t1 = ((sh >> (7 - i)) & 1) == 0;         // fg pixel
            float fo = t1 ? 0.25f * (1.f - pr_) * (1.f - pr_) * (fmaxf(-x, 0.f) + L)
                          : 0.75f * pr_ * pr_ * (fmaxf(x, 0.f) + L);
            facc += fo;
            float base = t1 ? (1.f - pr_) : pr_;
            s1 += base;
            s2 += base * dd;
            float tf = t1 ? 1.f : 0.f;
            iacc += tf * pr_;
            pacc += pr_ + tf;
            mx = fmaxf(mx, dd);
        }
    }
#pragma unroll
    for (int off = 32; off > 0; off >>= 1) {
        facc += __shfl_xor(facc, off);
        s1   += __shfl_xor(s1, off);
        s2   += __shfl_xor(s2, off);
        iacc += __shfl_xor(iacc, off);
        pacc += __shfl_xor(pacc, off);
        mx    = fmaxf(mx, __shfl_xor(mx, off));
    }
    if (lane == 0) {
        const int idx = s * NSTRIP + sig2;
        st_wt(&sacc[0 * NBLK + idx], s1);
        st_wt(&sacc[1 * NBLK + idx], s2);
        st_wt(&sacc[2 * NBLK + idx], iacc);
        st_wt(&sacc[3 * NBLK + idx], pacc);
        st_wt(&sacc[4 * NBLK + idx], mx);
        st_wt(&sacc[5 * NBLK + idx], facc);
        fence_release_add(c3);
    }

    // ---------------- phase 4: final reduction in block 0 only
    if (blockIdx.x != 0) return;
    for (int ss = 0; ss < NSAMP; ++ss) spin_wait(cnt + 2 * 512 + ss * 32, NSTRIP);
    float fsum = 0.f, bsum = 0.f, dsum = 0.f, isum = 0.f;
    for (int ss = 0; ss < NSAMP; ++ss) {
        int i0 = ss * NSTRIP + lane, i1 = i0 + 64;
        float t1 = ld_bp(&sacc[0 * NBLK + i0]) + ld_bp(&sacc[0 * NBLK + i1]);
        float t2 = ld_bp(&sacc[1 * NBLK + i0]) + ld_bp(&sacc[1 * NBLK + i1]);
        float ia = ld_bp(&sacc[2 * NBLK + i0]) + ld_bp(&sacc[2 * NBLK + i1]);
        float pa = ld_bp(&sacc[3 * NBLK + i0]) + ld_bp(&sacc[3 * NBLK + i1]);
        float mxs = fmaxf(ld_bp(&sacc[4 * NBLK + i0]), ld_bp(&sacc[4 * NBLK + i1]));
        float fa = ld_bp(&sacc[5 * NBLK + i0]) + ld_bp(&sacc[5 * NBLK + i1]);
        int   vv = ld_bpi(&blkflags[i0]) | ld_bpi(&blkflags[i1]);
#pragma unroll
        for (int off = 32; off > 0; off >>= 1) {
            t1 += __shfl_xor(t1, off);
            t2 += __shfl_xor(t2, off);
            ia += __shfl_xor(ia, off);
            pa += __shfl_xor(pa, off);
            fa += __shfl_xor(fa, off);
            mxs = fmaxf(mxs, __shfl_xor(mxs, off));
            vv |= __shfl_xor(vv, off);
        }
        bool hasb = (vv & 3) == 3;     // boundary nonempty (has_fg && has_bg)
        fsum += fa;
        float distsum = hasb ? ((mxs > 0.f) ? t2 / fmaxf(mxs, 1e-12f) : 0.f) : t1;
        bsum += t1 + distsum;
        dsum += (2.f * ia + 1e-6f) / (pa + 1e-6f);
        isum += (ia + 1e-6f) / (pa - ia + 1e-6f);
    }
    if (lane == 0) {
        float focal = fsum / NTOT_F;
        float bnd   = bsum / NTOT_F;
        float dice = 1.f - dsum / 16.f;
        float iou  = 1.f - isum / 16.f;
        float l0 = lv[0], l1 = lv[1], l2 = lv[2], l3 = lv[3];
        float total = expf(-l0) * focal + l0 + expf(-l1) * dice + l1
                    + expf(-l2) * bnd  + l2 + expf(-l3) * iou  + l3;
        out[0] = total; out[1] = focal; out[2] = dice; out[3] = bnd; out[4] = iou;
    }
}

extern "C" void kernel_launch(void* const* d_in, const int* in_sizes, int n_in,
                              void* d_out, int out_size, void* d_ws, size_t ws_size,
                              hipStream_t stream) {
    const float* pred = (const float*)d_in[0];
    const int*   tg   = (const int*)d_in[1];
    const float* lv   = (const float*)d_in[2];
    float* out = (float*)d_out;
    char* ws = (char*)d_ws;
    int*   cnt      = (int*)(ws + OFF_CNT);
    int*   blkflags = (int*)(ws + OFF_FLAGS);
    float* sacc     = (float*)(ws + OFF_SACC);
    float* mm1      = (float*)(ws + OFF_MM1);
    float* mm2      = (float*)(ws + OFF_MM2);
    float* Llast    = (float*)(ws + OFF_LLAST);
    float* Llast2   = (float*)(ws + OFF_LLAST2);

    // ws is poisoned between iterations -> sync counters must be zeroed each launch.
    hipMemsetAsync(cnt, 0, 6144, stream);
    fused_kernel<<<NBLK, 64, 0, stream>>>(pred, tg, lv, out, Llast, mm1, blkflags,
                                          Llast2, mm2, sacc, cnt);
}

// Round 8
// 112.649 us; speedup vs baseline: 4.9178x; 1.2686x over previous
//
#include <hip/hip_runtime.h>
#include <math.h>

#define A_W 0.955f
#define B_W 1.3693f
#define INF_W 1e6f
#define HDIM 512
#define WDIM 512
#define NPIX (HDIM*WDIM)
#define NSAMP 16
#define NTOT_F 4194304.0f
#define TST 4        // strip height
#define NSTRIP 128   // strips per sample
#define NBLK (NSAMP*NSTRIP)        // 2048
#define STRIP_COST (4.0f * A_W)    // min cost to propagate a boundary through one strip

// ws layout (bytes):
//  [0,8192):        int f1[2048]    (phase-1 done flags, per strip)
//  [8192,16384):    int f2[2048]    (phase-2 done flags, per flipped strip)
//  [16384,24576):   int f3[2048]    (phase-3 done flags)
//  [24576,32768):   int blkflags[2048]  (bit0=has_fg, bit1=has_bg)
//  [32768,81920):   float sacc[6][2048]
//  [81920,90112):   float mmax1[2048]   (max of Llast rows)
//  [90112,98304):   float mmax2[2048]   (max of Llast2 rows)
//  [1MB,5MB):       float Llast[16][128][512]
//  [5MB,9MB):       float Llast2[16][128][512]
#define OFF_F1     0
#define OFF_F2     8192
#define OFF_F3     16384
#define OFF_FLAGS  24576
#define OFF_SACC   32768
#define OFF_MMAX1  81920
#define OFF_MMAX2  90112
#define OFF_LLAST  (1u<<20)
#define OFF_LLAST2 (5u<<20)

typedef float f32x4 __attribute__((ext_vector_type(4)));

// ---- fence-free cross-block data movement --------------------------------------
// gfx950 XCD L2s are non-coherent; agent-scope ACQ/REL atomics emit whole-L2
// writeback/invalidate (round 4: ~420us floor). Proven scheme (rounds 5/6):
// payload via L1+L2-BYPASS ops (-> MALL, common point); producer drains with
// s_waitcnt vmcnt(0); SIGNAL IS A RELAXED ATOMIC RMW (fetch_add). Round-7
// post-mortem: replacing the RMW signal with a plain relaxed STORE broke
// visibility (phase-4 read unwritten sacc -> poison in out). The RMW is the one
// signal mechanism with passing evidence — keep it, but aim each RMW at a
// DISTINCT per-strip flag (2048 addresses, <=16 RMWs per 64B line) so round-6's
// hot-line serialization (128 RMWs/line + 2048-RMW gate) does not return.
__device__ __forceinline__ void st_wti(int* p, int v) {
    __hip_atomic_store(p, v, __ATOMIC_RELAXED, __HIP_MEMORY_SCOPE_AGENT);
}
__device__ __forceinline__ int ld_bpi(const int* p) {
    return __hip_atomic_load((int*)p, __ATOMIC_RELAXED, __HIP_MEMORY_SCOPE_AGENT);
}
__device__ __forceinline__ void st_wt(float* p, float v) {
    st_wti((int*)p, __float_as_int(v));
}
__device__ __forceinline__ float ld_bp(const float* p) {
    return __int_as_float(ld_bpi((const int*)p));
}
// 16B-wide L1+L2-bypass ops. "=&v" early-clobber: dest must not overlap the
// address pair (load replay hazard). Results readable only after vm_wait0().
__device__ __forceinline__ f32x4 ld_bp4(const float* p) {
    f32x4 r;
    asm volatile("global_load_dwordx4 %0, %1, off sc0 sc1"
                 : "=&v"(r) : "v"(p) : "memory");
    return r;
}
__device__ __forceinline__ void st_wt4(float* p, f32x4 v) {
    asm volatile("global_store_dwordx4 %0, %1, off sc0 sc1"
                 :: "v"(p), "v"(v) : "memory");
}
__device__ __forceinline__ void vm_wait0() {
    asm volatile("s_waitcnt vmcnt(0)" ::: "memory");
    __builtin_amdgcn_sched_barrier(0);   // block reg-only hoisting past the wait
}

// Publish: drain this wave's write-through stores to MALL (vmcnt is wave-level,
// covers all 64 lanes), then bump the per-strip flag with a relaxed RMW — the
// proven signal mechanism (rounds 5/6).
__device__ __forceinline__ void flag_post(int* f, int lane) {
    asm volatile("s_waitcnt vmcnt(0)" ::: "memory");
    if (lane == 0)
        __hip_atomic_fetch_add(f, 1, __ATOMIC_RELAXED, __HIP_MEMORY_SCOPE_AGENT);
}
__device__ __forceinline__ void wait_flag(const int* f) {
    while (!__all(ld_bpi(f) != 0))
        __builtin_amdgcn_s_sleep(2);
    asm volatile("" ::: "memory");   // no payload reads hoisted above the spin
}
// wait until f[k] != 0 for all k in [k0, kend); kend-k0 <= 127
__device__ __forceinline__ void wait_flags_range(const int* f, int k0, int kend,
                                                 int lane) {
    if (k0 >= kend) return;
    for (;;) {
        int k1 = k0 + lane, k2 = k0 + 64 + lane;
        int v1 = (k1 < kend) ? ld_bpi(&f[k1]) : 1;
        int v2 = (k2 < kend) ? ld_bpi(&f[k2]) : 1;
        if (__all((v1 != 0) & (v2 != 0))) break;
        __builtin_amdgcn_s_sleep(2);
    }
    asm volatile("" ::: "memory");
}

// DPP move with INF fill (floats).
template<int CTRL, int RMASK>
__device__ __forceinline__ float dpp_mov_inf(float x) {
    return __int_as_float(__builtin_amdgcn_update_dpp(
        __float_as_int(INF_W), __float_as_int(x), CTRL, RMASK, 0xF, false));
}
template<int CTRL>
__device__ __forceinline__ int dpp_mov0_i(int x) {
    return __builtin_amdgcn_update_dpp(0, x, CTRL, 0xF, 0xF, true);
}

__device__ __forceinline__ float wave_prefix_min_incl(float t) {
    t = fminf(t, dpp_mov_inf<0x111,0xF>(t));
    t = fminf(t, dpp_mov_inf<0x112,0xF>(t));
    t = fminf(t, dpp_mov_inf<0x114,0xF>(t));
    t = fminf(t, dpp_mov_inf<0x118,0xF>(t));
    t = fminf(t, dpp_mov_inf<0x142,0xA>(t));
    t = fminf(t, dpp_mov_inf<0x143,0xC>(t));
    return t;
}

__device__ __forceinline__ void cummin_row(const float* jc, float* v) {
    float g[8];
#pragma unroll
    for (int i = 0; i < 8; ++i) g[i] = v[i] - jc[i];
    float c1[8];
    c1[0] = g[0];
#pragma unroll
    for (int i = 1; i < 8; ++i) c1[i] = fminf(g[i], g[i-1]);
    float c2[8];
    c2[0] = c1[0]; c2[1] = c1[1];
#pragma unroll
    for (int i = 2; i < 8; ++i) c2[i] = fminf(c1[i], c1[i-2]);
    float cj[8];
    cj[0] = c2[0]; cj[1] = c2[1]; cj[2] = c2[2]; cj[3] = c2[3];
#pragma unroll
    for (int i = 4; i < 8; ++i) cj[i] = fminf(c2[i], c2[i-4]);
    float t  = wave_prefix_min_incl(cj[7]);
    float ex = dpp_mov_inf<0x138,0xF>(t);
#pragma unroll
    for (int i = 0; i < 8; ++i) v[i] = jc[i] + fminf(cj[i], ex);
}

__device__ __forceinline__ void row_step(const float* jc, float* prev, const float* drow) {
    float lIn = dpp_mov_inf<0x138,0xF>(prev[7]);
    float rIn = dpp_mov_inf<0x130,0xF>(prev[0]);
    float m[8];
#pragma unroll
    for (int i = 0; i < 8; ++i) {
        float up = prev[i] + A_W;
        float ul = ((i == 0) ? lIn : prev[i-1]) + B_W;
        float ur = ((i == 7) ? rIn : prev[i+1]) + B_W;
        m[i] = fminf(fminf(drow[i], up), fminf(ul, ur));
    }
    cummin_row(jc, m);
#pragma unroll
    for (int i = 0; i < 8; ++i) prev[i] = m[i];
}

// 4 fused T3 steps (exact, INF outside grid). T3^4 == one call (TST==4).
__device__ __forceinline__ void t3x4(float* b) {
    float e[16];
#pragma unroll
    for (int k = 0; k < 4; ++k) e[k]    = dpp_mov_inf<0x138,0xF>(b[4+k]);
#pragma unroll
    for (int k = 0; k < 8; ++k) e[4+k]  = b[k];
#pragma unroll
    for (int k = 0; k < 4; ++k) e[12+k] = dpp_mov_inf<0x130,0xF>(b[k]);
    const float w0 = 4.f*A_W, w1 = 3.f*A_W + B_W, w2 = 2.f*A_W + 2.f*B_W;
    const float w3 = A_W + 3.f*B_W, w4 = 4.f*B_W;
#pragma unroll
    for (int i = 0; i < 8; ++i) {
        float m = e[i+4] + w0;
        m = fminf(m, fminf(e[i+3], e[i+5]) + w1);
        m = fminf(m, fminf(e[i+2], e[i+6]) + w2);
        m = fminf(m, fminf(e[i+1], e[i+7]) + w3);
        m = fminf(m, fminf(e[i+0], e[i+8]) + w4);
        b[i] = m;
    }
}

struct RowBits { int efg; int ebg; int rawbg; };

__device__ __forceinline__ RowBits make_rowbits(uint4 a, uint4 b) {
    int fg = ((a.x!=0u)?1:0) | ((a.y!=0u)?2:0) | ((a.z!=0u)?4:0) | ((a.w!=0u)?8:0)
           | ((b.x!=0u)?16:0) | ((b.y!=0u)?32:0) | ((b.z!=0u)?64:0) | ((b.w!=0u)?128:0);
    int bg = (~fg) & 0xFF;
    int lf = dpp_mov0_i<0x138>(fg), rf = dpp_mov0_i<0x130>(fg);
    int lb = dpp_mov0_i<0x138>(bg), rb = dpp_mov0_i<0x130>(bg);
    RowBits r;
    r.efg = (fg | (fg<<1) | (fg>>1) | ((lf>>7)&1) | ((rf&1)<<7)) & 0xFF;
    r.ebg = (bg | (bg<<1) | (bg>>1) | ((lb>>7)&1) | ((rb&1)<<7)) & 0xFF;
    r.rawbg = bg;
    return r;
}

__device__ __forceinline__ RowBits loadrow_bits(const int* tgb, int rr, int c0) {
    if (rr < 0 || rr >= HDIM) { RowBits z; z.efg = 0; z.ebg = 0; z.rawbg = 0; return z; }
    const uint4* p = (const uint4*)(tgb + (size_t)rr * WDIM + c0);
    return make_rowbits(p[0], p[1]);
}

// store max of an L row (prev[8] across wave) into mmax (write-through)
__device__ __forceinline__ void store_max(const float* prev, float* __restrict__ mmax,
                                          int idx, int lane) {
    float mx = prev[0];
#pragma unroll
    for (int i = 1; i < 8; ++i) mx = fmaxf(mx, prev[i]);
#pragma unroll
    for (int off = 32; off > 0; off >>= 1) mx = fmaxf(mx, __shfl_xor(mx, off));
    if (lane == 0) st_wt(&mmax[idx], mx);
}

// Exact boundary via chain walk over strips [k0, n-1]. Caller guarantees flags
// [k0, n-1] observed. 16B bypass loads issued before t3x4/cummin to hide MALL
// latency; results consumed only after vm_wait0().
__device__ __forceinline__ void chain_walk(const float* __restrict__ Lb, int k0, int n,
                                           const float* jc, int c0, float* prev) {
    float b[8];
    const float* Lr = Lb + (size_t)k0 * WDIM + c0;
    f32x4 l0 = ld_bp4(Lr);
    f32x4 l1 = ld_bp4(Lr + 4);
    vm_wait0();
#pragma unroll
    for (int i = 0; i < 4; ++i) { b[i] = l0[i]; b[4 + i] = l1[i]; }
    for (int sg = k0 + 1; sg < n; ++sg) {
        const float* Ls = Lb + (size_t)sg * WDIM + c0;
        f32x4 m0 = ld_bp4(Ls);
        f32x4 m1 = ld_bp4(Ls + 4);
        t3x4(b);                                 // T3^4 exact (TST==4)
        cummin_row(jc, b);
        vm_wait0();
#pragma unroll
        for (int i = 0; i < 4; ++i) {
            b[i]     = fminf(b[i],     m0[i]);
            b[4 + i] = fminf(b[4 + i], m1[i]);
        }
    }
#pragma unroll
    for (int i = 0; i < 8; ++i) prev[i] = b[i];
}

// k0 from ub = maxL[n-1]: keep strips with STRIP_COST*(n-1-k) <= ub (distances
// >= 0 make this sufficient; 1e-3 margin => rounding can only KEEP extra strips,
// never drop a tied one -> exact). g clamped to [0,127] defensively (a garbage
// negative ub must not produce an out-of-range k0).
__device__ __forceinline__ int k0_from_ub(float ub, int n) {
    int g = (int)(ub * (1.0f / STRIP_COST) + 1e-3f);
    if (g < 0) g = 0;
    if (g > NSTRIP - 1) g = NSTRIP - 1;
    int k0 = n - 1 - g;
    return (k0 < 0) ? 0 : k0;
}

// =====================================================================================
// Fused kernel: all 3 strip phases + final reduce in ONE dispatch.
// Co-residency by construction: __launch_bounds__(64,2) caps VGPR at 256; any
// VGPR<=256 gives >=2 waves/SIMD -> >=8 single-wave blocks/CU -> >=2048 slots =
// grid size (LDS 8KB -> 20/CU, not binding) => waits cannot deadlock (deps form
// a DAG over strips). (64,4) forbidden: VGPR->64, ~90MB scratch spill (round 3).
// =====================================================================================
__global__ __launch_bounds__(64, 2) void fused_kernel(
        const float* __restrict__ pred, const int* __restrict__ tg,
        const float* __restrict__ lv, float* __restrict__ out,
        float* __restrict__ Llast, float* __restrict__ mmax1, int* __restrict__ blkflags,
        float* __restrict__ Llast2, float* __restrict__ mmax2, float* __restrict__ sacc,
        int* f1, int* f2, int* f3) {
    const int s = blockIdx.x >> 7, sig = blockIdx.x & 127;
    const int lane = threadIdx.x;
    const int c0 = lane * 8;
    const int* tgb = tg + (size_t)s * NPIX;
    const int R0 = sig * TST;
    const int base = s * NSTRIP;
    float jc[8];
#pragma unroll
    for (int i = 0; i < 8; ++i) jc[i] = A_W * (float)(c0 + i);

    __shared__ float lds[TST][WDIM];   // 8 KB; single-wave block

    // ---------------- phase 1: local strip scan (INF incoming) -> Llast/mmax1/flags
    unsigned int smaskp = 0u, rawbgp = 0u;   // byte t = row t's 8-bit masks
    RowBits rA = loadrow_bits(tgb, R0 - 1, c0);
    RowBits rB = loadrow_bits(tgb, R0, c0);
    float prev[8];
#pragma unroll
    for (int i = 0; i < 8; ++i) prev[i] = INF_W;
    int fgor = 0, bgor = 0;
#pragma unroll
    for (int t = 0; t < TST; ++t) {
        RowBits rC = loadrow_bits(tgb, R0 + t + 1, c0);
        fgor |= (~rB.rawbg) & 0xFF;
        bgor |= rB.rawbg;
        int smask = (rA.efg | rB.efg | rC.efg) & (rA.ebg | rB.ebg | rC.ebg);
        smaskp |= ((unsigned int)smask) << (8 * t);
        rawbgp |= ((unsigned int)rB.rawbg) << (8 * t);
        float dr[8];
#pragma unroll
        for (int i = 0; i < 8; ++i) dr[i] = ((smask >> i) & 1) ? 0.f : INF_W;
        row_step(jc, prev, dr);
        rA = rB; rB = rC;
    }
    {
        float* Lr = Llast + ((size_t)base + sig) * WDIM + c0;
        f32x4 v0 = {prev[0], prev[1], prev[2], prev[3]};
        f32x4 v1 = {prev[4], prev[5], prev[6], prev[7]};
        st_wt4(Lr, v0);
        st_wt4(Lr + 4, v1);
        store_max(prev, mmax1, base + sig, lane);
        int wf = __any(fgor != 0) ? 1 : 0;
        int wb = __any(bgor != 0) ? 2 : 0;
        if (lane == 0) st_wti(&blkflags[blockIdx.x], wf | wb);
    }
    flag_post(&f1[base + sig], lane);

    // ---------------- phase 2: exact pass-1 rows -> LDS; flipped local scan -> Llast2/mmax2
    if (sig == 0) {
#pragma unroll
        for (int i = 0; i < 8; ++i) prev[i] = INF_W;
    } else {
        wait_flag(&f1[base + sig - 1]);
        float ub = ld_bp(&mmax1[base + sig - 1]);
        int k0 = k0_from_ub(ub, sig);
        wait_flags_range(f1 + base, k0, sig - 1, lane);
        chain_walk(Llast + (size_t)base * WDIM, k0, sig, jc, c0, prev);
    }
#pragma unroll
    for (int t = 0; t < TST; ++t) {
        unsigned int sm = (smaskp >> (8 * t)) & 0xFFu;
        float dr[8];
#pragma unroll
        for (int i = 0; i < 8; ++i) dr[i] = ((sm >> i) & 1u) ? 0.f : INF_W;
        row_step(jc, prev, dr);
        *(float4*)&lds[t][c0]     = make_float4(prev[0], prev[1], prev[2], prev[3]);
        *(float4*)&lds[t][c0 + 4] = make_float4(prev[4], prev[5], prev[6], prev[7]);
    }
    __syncthreads();
    // flipped (pass-2) local scan over this strip, INF incoming
#pragma unroll
    for (int i = 0; i < 8; ++i) prev[i] = INF_W;
#pragma unroll
    for (int t2 = 0; t2 < TST; ++t2) {
        float4 a = *(const float4*)&lds[TST - 1 - t2][504 - c0];
        float4 q = *(const float4*)&lds[TST - 1 - t2][508 - c0];
        float dr[8];
        dr[7]=a.x; dr[6]=a.y; dr[5]=a.z; dr[4]=a.w;
        dr[3]=q.x; dr[2]=q.y; dr[1]=q.z; dr[0]=q.w;
        row_step(jc, prev, dr);
    }
    const int sig2 = NSTRIP - 1 - sig;   // flipped strip index == this block's own rows
    {
        float* Lr = Llast2 + ((size_t)base + sig2) * WDIM + c0;
        f32x4 v0 = {prev[0], prev[1], prev[2], prev[3]};
        f32x4 v1 = {prev[4], prev[5], prev[6], prev[7]};
        st_wt4(Lr, v0);
        st_wt4(Lr + 4, v1);
        store_max(prev, mmax2, base + sig2, lane);
    }
    flag_post(&f2[base + sig2], lane);

    // ---------------- phase 3: exact pass-2 rows (dr from own LDS) + fused loss -> sacc
    if (sig2 == 0) {
#pragma unroll
        for (int i = 0; i < 8; ++i) prev[i] = INF_W;
    } else {
        wait_flag(&f2[base + sig2 - 1]);
        float ub = ld_bp(&mmax2[base + sig2 - 1]);
        int k0 = k0_from_ub(ub, sig2);
        wait_flags_range(f2 + base, k0, sig2 - 1, lane);
        chain_walk(Llast2 + (size_t)base * WDIM, k0, sig2, jc, c0, prev);
    }
    const size_t sb = (size_t)s * NPIX;
    float mx = 0.f, facc = 0.f, s1 = 0.f, s2 = 0.f, iacc = 0.f, pacc = 0.f;
#pragma unroll
    for (int t = 0; t < TST; ++t) {
        const int pr = R0 + (TST - 1) - t;        // == HDIM-1-(sig2*TST+t), own strip rows
        float4 a  = *(const float4*)&lds[TST - 1 - t][504 - c0];
        float4 b4 = *(const float4*)&lds[TST - 1 - t][508 - c0];
        float dr[8];
        dr[7]=a.x;  dr[6]=a.y;  dr[5]=a.z;  dr[4]=a.w;
        dr[3]=b4.x; dr[2]=b4.y; dr[1]=b4.z; dr[0]=b4.w;
        const size_t rbase = sb + (size_t)pr * WDIM + (WDIM - 8 - c0);
        float4 xa = *(const float4*)(pred + rbase);
        float4 xb = *(const float4*)(pred + rbase + 4);
        float px[8];
        px[7]=xa.x; px[6]=xa.y; px[5]=xa.z; px[4]=xa.w;
        px[3]=xb.x; px[2]=xb.y; px[1]=xb.z; px[0]=xb.w;
        // target bits for reversed columns: col 511-c0-i lives in lane 63-lane, bit 7-i
        int sh = __shfl((int)((rawbgp >> (8 * (TST - 1 - t))) & 0xFFu), 63 - lane);
        row_step(jc, prev, dr);
#pragma unroll
        for (int i = 0; i < 8; ++i) {
            float x = px[i];
            float dd = prev[i];
            float e = __expf(-fabsf(x));
            float inv = 1.f / (1.f + e);
            float pr_ = (x >= 0.f) ? inv : (1.f - inv);   // sigmoid(x)
            float L = __logf(1.f + e);                    // softplus(-|x|)
            bool t1 = ((sh >> (7 - i)) & 1) == 0;         // fg pixel
            float fo = t1 ? 0.25f * (1.f - pr_) * (1.f - pr_) * (fmaxf(-x, 0.f) + L)
                          : 0.75f * pr_ * pr_ * (fmaxf(x, 0.f) + L);
            facc += fo;
            float base_ = t1 ? (1.f - pr_) : pr_;
            s1 += base_;
            s2 += base_ * dd;
            float tf = t1 ? 1.f : 0.f;
            iacc += tf * pr_;
            pacc += pr_ + tf;
            mx = fmaxf(mx, dd);
        }
    }
#pragma unroll
    for (int off = 32; off > 0; off >>= 1) {
        facc += __shfl_xor(facc, off);
        s1   += __shfl_xor(s1, off);
        s2   += __shfl_xor(s2, off);
        iacc += __shfl_xor(iacc, off);
        pacc += __shfl_xor(pacc, off);
        mx    = fmaxf(mx, __shfl_xor(mx, off));
    }
    if (lane == 0) {
        const int idx = base + sig2;
        st_wt(&sacc[0 * NBLK + idx], s1);
        st_wt(&sacc[1 * NBLK + idx], s2);
        st_wt(&sacc[2 * NBLK + idx], iacc);
        st_wt(&sacc[3 * NBLK + idx], pacc);
        st_wt(&sacc[4 * NBLK + idx], mx);
        st_wt(&sacc[5 * NBLK + idx], facc);
    }
    flag_post(&f3[blockIdx.x], lane);

    // ---------------- phase 4: final reduction in block 0 only
    if (blockIdx.x != 0) return;
    for (;;) {
        int ok = 1;
#pragma unroll
        for (int w = 0; w < 32; ++w) ok &= (ld_bpi(&f3[w * 64 + lane]) != 0);
        if (__all(ok)) break;
        __builtin_amdgcn_s_sleep(8);
    }
    asm volatile("" ::: "memory");
    float fsum = 0.f, bsum = 0.f, dsum = 0.f, isum = 0.f;
    for (int ss = 0; ss < NSAMP; ++ss) {
        int i0 = ss * NSTRIP + lane, i1 = i0 + 64;
        float t1 = ld_bp(&sacc[0 * NBLK + i0]) + ld_bp(&sacc[0 * NBLK + i1]);
        float t2 = ld_bp(&sacc[1 * NBLK + i0]) + ld_bp(&sacc[1 * NBLK + i1]);
        float ia = ld_bp(&sacc[2 * NBLK + i0]) + ld_bp(&sacc[2 * NBLK + i1]);
        float pa = ld_bp(&sacc[3 * NBLK + i0]) + ld_bp(&sacc[3 * NBLK + i1]);
        float mxs = fmaxf(ld_bp(&sacc[4 * NBLK + i0]), ld_bp(&sacc[4 * NBLK + i1]));
        float fa = ld_bp(&sacc[5 * NBLK + i0]) + ld_bp(&sacc[5 * NBLK + i1]);
        int   vv = ld_bpi(&blkflags[i0]) | ld_bpi(&blkflags[i1]);
#pragma unroll
        for (int off = 32; off > 0; off >>= 1) {
            t1 += __shfl_xor(t1, off);
            t2 += __shfl_xor(t2, off);
            ia += __shfl_xor(ia, off);
            pa += __shfl_xor(pa, off);
            fa += __shfl_xor(fa, off);
            mxs = fmaxf(mxs, __shfl_xor(mxs, off));
            vv |= __shfl_xor(vv, off);
        }
        bool hasb = (vv & 3) == 3;     // boundary nonempty (has_fg && has_bg)
        fsum += fa;
        float distsum = hasb ? ((mxs > 0.f) ? t2 / fmaxf(mxs, 1e-12f) : 0.f) : t1;
        bsum += t1 + distsum;
        dsum += (2.f * ia + 1e-6f) / (pa + 1e-6f);
        isum += (ia + 1e-6f) / (pa - ia + 1e-6f);
    }
    if (lane == 0) {
        float focal = fsum / NTOT_F;
        float bnd   = bsum / NTOT_F;
        float dice = 1.f - dsum / 16.f;
        float iou  = 1.f - isum / 16.f;
        float l0 = lv[0], l1 = lv[1], l2 = lv[2], l3 = lv[3];
        float total = expf(-l0) * focal + l0 + expf(-l1) * dice + l1
                    + expf(-l2) * bnd  + l2 + expf(-l3) * iou  + l3;
        out[0] = total; out[1] = focal; out[2] = dice; out[3] = bnd; out[4] = iou;
    }
}

extern "C" void kernel_launch(void* const* d_in, const int* in_sizes, int n_in,
                              void* d_out, int out_size, void* d_ws, size_t ws_size,
                              hipStream_t stream) {
    const float* pred = (const float*)d_in[0];
    const int*   tg   = (const int*)d_in[1];
    const float* lv   = (const float*)d_in[2];
    float* out = (float*)d_out;
    char* ws = (char*)d_ws;
    int*   f1       = (int*)(ws + OFF_F1);
    int*   f2       = (int*)(ws + OFF_F2);
    int*   f3       = (int*)(ws + OFF_F3);
    int*   blkflags = (int*)(ws + OFF_FLAGS);
    float* sacc     = (float*)(ws + OFF_SACC);
    float* mmax1    = (float*)(ws + OFF_MMAX1);
    float* mmax2    = (float*)(ws + OFF_MMAX2);
    float* Llast    = (float*)(ws + OFF_LLAST);
    float* Llast2   = (float*)(ws + OFF_LLAST2);

    // ws is poisoned between iterations -> flags must be zeroed each launch.
    hipMemsetAsync(ws, 0, 24576, stream);
    fused_kernel<<<NBLK, 64, 0, stream>>>(pred, tg, lv, out, Llast, mmax1, blkflags,
                                          Llast2, mmax2, sacc, f1, f2, f3);
}

// Round 10
// 111.995 us; speedup vs baseline: 4.9466x; 1.0058x over previous
//
#include <hip/hip_runtime.h>
#include <math.h>

#define A_W 0.955f
#define B_W 1.3693f
#define INF_W 1e6f
#define HDIM 512
#define WDIM 512
#define NPIX (HDIM*WDIM)
#define NSAMP 16
#define NTOT_F 4194304.0f
#define TST 4        // strip height
#define NSTRIP 128   // strips per sample
#define NBLK (NSAMP*NSTRIP)        // 2048
#define STRIP_COST (4.0f * A_W)    // min cost to propagate a boundary through one strip

// ws layout (bytes):
//  [0,8192):        int f1[2048]    (phase-1 done flags, per strip)
//  [8192,16384):    int f2[2048]    (phase-2 done flags, per flipped strip)
//  [16384,24576):   int f3[2048]    (phase-3 done flags)
//  [24576,32768):   int blkflags[2048]  (bit0=has_fg, bit1=has_bg)
//  [32768,81920):   float sacc[6][2048]
//  [81920,90112):   float mmax1[2048]   (max of Llast rows)
//  [90112,98304):   float mmax2[2048]   (max of Llast2 rows)
//  [1MB,5MB):       float Llast[16][128][512]
//  [5MB,9MB):       float Llast2[16][128][512]
#define OFF_F1     0
#define OFF_F2     8192
#define OFF_F3     16384
#define OFF_FLAGS  24576
#define OFF_SACC   32768
#define OFF_MMAX1  81920
#define OFF_MMAX2  90112
#define OFF_LLAST  (1u<<20)
#define OFF_LLAST2 (5u<<20)

typedef float f32x4 __attribute__((ext_vector_type(4)));

// ---- fence-free cross-block data movement --------------------------------------
// gfx950 XCD L2s are non-coherent; agent-scope ACQ/REL atomics emit whole-L2
// writeback/invalidate (round 4: ~420us floor). Proven scheme (rounds 5/6/8):
// payload via L1+L2-BYPASS ops (-> MALL, common point); producer drains with
// s_waitcnt vmcnt(0); SIGNAL = RELAXED ATOMIC RMW on a per-strip flag (2048
// distinct addresses -> no hot-line serialization; plain-store signal broke
// visibility in round 7 — do not regress).
// ROUND-9 LESSON: bundling {batched tg loads, pred prefetch spanning the phase-3
// wait} broke correctness (absmax 73.8, focal-scale error). Reverted to this
// exact round-8 state (passed, 112.65us). Any future MLP change must be ONE
// change per round and must not hold prefetch state across the sync region.
__device__ __forceinline__ void st_wti(int* p, int v) {
    __hip_atomic_store(p, v, __ATOMIC_RELAXED, __HIP_MEMORY_SCOPE_AGENT);
}
__device__ __forceinline__ int ld_bpi(const int* p) {
    return __hip_atomic_load((int*)p, __ATOMIC_RELAXED, __HIP_MEMORY_SCOPE_AGENT);
}
__device__ __forceinline__ void st_wt(float* p, float v) {
    st_wti((int*)p, __float_as_int(v));
}
__device__ __forceinline__ float ld_bp(const float* p) {
    return __int_as_float(ld_bpi((const int*)p));
}
// 16B-wide L1+L2-bypass ops. "=&v" early-clobber: dest must not overlap the
// address pair. Results readable only after vm_wait0().
__device__ __forceinline__ f32x4 ld_bp4(const float* p) {
    f32x4 r;
    asm volatile("global_load_dwordx4 %0, %1, off sc0 sc1"
                 : "=&v"(r) : "v"(p) : "memory");
    return r;
}
__device__ __forceinline__ void st_wt4(float* p, f32x4 v) {
    asm volatile("global_store_dwordx4 %0, %1, off sc0 sc1"
                 :: "v"(p), "v"(v) : "memory");
}
__device__ __forceinline__ void vm_wait0() {
    asm volatile("s_waitcnt vmcnt(0)" ::: "memory");
    __builtin_amdgcn_sched_barrier(0);   // block reg-only hoisting past the wait
}

// Publish: drain this wave's write-through stores to MALL (vmcnt is wave-level,
// covers all 64 lanes), then bump the per-strip flag with a relaxed RMW.
__device__ __forceinline__ void flag_post(int* f, int lane) {
    asm volatile("s_waitcnt vmcnt(0)" ::: "memory");
    if (lane == 0)
        __hip_atomic_fetch_add(f, 1, __ATOMIC_RELAXED, __HIP_MEMORY_SCOPE_AGENT);
}
__device__ __forceinline__ void wait_flag(const int* f) {
    while (!__all(ld_bpi(f) != 0))
        __builtin_amdgcn_s_sleep(2);
    asm volatile("" ::: "memory");   // no payload reads hoisted above the spin
}
// wait until f[k] != 0 for all k in [k0, kend); kend-k0 <= 127
__device__ __forceinline__ void wait_flags_range(const int* f, int k0, int kend,
                                                 int lane) {
    if (k0 >= kend) return;
    for (;;) {
        int k1 = k0 + lane, k2 = k0 + 64 + lane;
        int v1 = (k1 < kend) ? ld_bpi(&f[k1]) : 1;
        int v2 = (k2 < kend) ? ld_bpi(&f[k2]) : 1;
        if (__all((v1 != 0) & (v2 != 0))) break;
        __builtin_amdgcn_s_sleep(2);
    }
    asm volatile("" ::: "memory");
}

// DPP move with INF fill (floats).
template<int CTRL, int RMASK>
__device__ __forceinline__ float dpp_mov_inf(float x) {
    return __int_as_float(__builtin_amdgcn_update_dpp(
        __float_as_int(INF_W), __float_as_int(x), CTRL, RMASK, 0xF, false));
}
template<int CTRL>
__device__ __forceinline__ int dpp_mov0_i(int x) {
    return __builtin_amdgcn_update_dpp(0, x, CTRL, 0xF, 0xF, true);
}

__device__ __forceinline__ float wave_prefix_min_incl(float t) {
    t = fminf(t, dpp_mov_inf<0x111,0xF>(t));
    t = fminf(t, dpp_mov_inf<0x112,0xF>(t));
    t = fminf(t, dpp_mov_inf<0x114,0xF>(t));
    t = fminf(t, dpp_mov_inf<0x118,0xF>(t));
    t = fminf(t, dpp_mov_inf<0x142,0xA>(t));
    t = fminf(t, dpp_mov_inf<0x143,0xC>(t));
    return t;
}

__device__ __forceinline__ void cummin_row(const float* jc, float* v) {
    float g[8];
#pragma unroll
    for (int i = 0; i < 8; ++i) g[i] = v[i] - jc[i];
    float c1[8];
    c1[0] = g[0];
#pragma unroll
    for (int i = 1; i < 8; ++i) c1[i] = fminf(g[i], g[i-1]);
    float c2[8];
    c2[0] = c1[0]; c2[1] = c1[1];
#pragma unroll
    for (int i = 2; i < 8; ++i) c2[i] = fminf(c1[i], c1[i-2]);
    float cj[8];
    cj[0] = c2[0]; cj[1] = c2[1]; cj[2] = c2[2]; cj[3] = c2[3];
#pragma unroll
    for (int i = 4; i < 8; ++i) cj[i] = fminf(c2[i], c2[i-4]);
    float t  = wave_prefix_min_incl(cj[7]);
    float ex = dpp_mov_inf<0x138,0xF>(t);
#pragma unroll
    for (int i = 0; i < 8; ++i) v[i] = jc[i] + fminf(cj[i], ex);
}

__device__ __forceinline__ void row_step(const float* jc, float* prev, const float* drow) {
    float lIn = dpp_mov_inf<0x138,0xF>(prev[7]);
    float rIn = dpp_mov_inf<0x130,0xF>(prev[0]);
    float m[8];
#pragma unroll
    for (int i = 0; i < 8; ++i) {
        float up = prev[i] + A_W;
        float ul = ((i == 0) ? lIn : prev[i-1]) + B_W;
        float ur = ((i == 7) ? rIn : prev[i+1]) + B_W;
        m[i] = fminf(fminf(drow[i], up), fminf(ul, ur));
    }
    cummin_row(jc, m);
#pragma unroll
    for (int i = 0; i < 8; ++i) prev[i] = m[i];
}

// 4 fused T3 steps (exact, INF outside grid). T3^4 == one call (TST==4).
__device__ __forceinline__ void t3x4(float* b) {
    float e[16];
#pragma unroll
    for (int k = 0; k < 4; ++k) e[k]    = dpp_mov_inf<0x138,0xF>(b[4+k]);
#pragma unroll
    for (int k = 0; k < 8; ++k) e[4+k]  = b[k];
#pragma unroll
    for (int k = 0; k < 4; ++k) e[12+k] = dpp_mov_inf<0x130,0xF>(b[k]);
    const float w0 = 4.f*A_W, w1 = 3.f*A_W + B_W, w2 = 2.f*A_W + 2.f*B_W;
    const float w3 = A_W + 3.f*B_W, w4 = 4.f*B_W;
#pragma unroll
    for (int i = 0; i < 8; ++i) {
        float m = e[i+4] + w0;
        m = fminf(m, fminf(e[i+3], e[i+5]) + w1);
        m = fminf(m, fminf(e[i+2], e[i+6]) + w2);
        m = fminf(m, fminf(e[i+1], e[i+7]) + w3);
        m = fminf(m, fminf(e[i+0], e[i+8]) + w4);
        b[i] = m;
    }
}

struct RowBits { int efg; int ebg; int rawbg; };

__device__ __forceinline__ RowBits make_rowbits(uint4 a, uint4 b) {
    int fg = ((a.x!=0u)?1:0) | ((a.y!=0u)?2:0) | ((a.z!=0u)?4:0) | ((a.w!=0u)?8:0)
           | ((b.x!=0u)?16:0) | ((b.y!=0u)?32:0) | ((b.z!=0u)?64:0) | ((b.w!=0u)?128:0);
    int bg = (~fg) & 0xFF;
    int lf = dpp_mov0_i<0x138>(fg), rf = dpp_mov0_i<0x130>(fg);
    int lb = dpp_mov0_i<0x138>(bg), rb = dpp_mov0_i<0x130>(bg);
    RowBits r;
    r.efg = (fg | (fg<<1) | (fg>>1) | ((lf>>7)&1) | ((rf&1)<<7)) & 0xFF;
    r.ebg = (bg | (bg<<1) | (bg>>1) | ((lb>>7)&1) | ((rb&1)<<7)) & 0xFF;
    r.rawbg = bg;
    return r;
}

__device__ __forceinline__ RowBits loadrow_bits(const int* tgb, int rr, int c0) {
    if (rr < 0 || rr >= HDIM) { RowBits z; z.efg = 0; z.ebg = 0; z.rawbg = 0; return z; }
    const uint4* p = (const uint4*)(tgb + (size_t)rr * WDIM + c0);
    return make_rowbits(p[0], p[1]);
}

// store max of an L row (prev[8] across wave) into mmax (write-through)
__device__ __forceinline__ void store_max(const float* prev, float* __restrict__ mmax,
                                          int idx, int lane) {
    float mx = prev[0];
#pragma unroll
    for (int i = 1; i < 8; ++i) mx = fmaxf(mx, prev[i]);
#pragma unroll
    for (int off = 32; off > 0; off >>= 1) mx = fmaxf(mx, __shfl_xor(mx, off));
    if (lane == 0) st_wt(&mmax[idx], mx);
}

// Exact boundary via chain walk over strips [k0, n-1]. Caller guarantees flags
// [k0, n-1] observed. 16B bypass loads issued before t3x4/cummin to hide MALL
// latency; results consumed only after vm_wait0().
__device__ __forceinline__ void chain_walk(const float* __restrict__ Lb, int k0, int n,
                                           const float* jc, int c0, float* prev) {
    float b[8];
    const float* Lr = Lb + (size_t)k0 * WDIM + c0;
    f32x4 l0 = ld_bp4(Lr);
    f32x4 l1 = ld_bp4(Lr + 4);
    vm_wait0();
#pragma unroll
    for (int i = 0; i < 4; ++i) { b[i] = l0[i]; b[4 + i] = l1[i]; }
    for (int sg = k0 + 1; sg < n; ++sg) {
        const float* Ls = Lb + (size_t)sg * WDIM + c0;
        f32x4 m0 = ld_bp4(Ls);
        f32x4 m1 = ld_bp4(Ls + 4);
        t3x4(b);                                 // T3^4 exact (TST==4)
        cummin_row(jc, b);
        vm_wait0();
#pragma unroll
        for (int i = 0; i < 4; ++i) {
            b[i]     = fminf(b[i],     m0[i]);
            b[4 + i] = fminf(b[4 + i], m1[i]);
        }
    }
#pragma unroll
    for (int i = 0; i < 8; ++i) prev[i] = b[i];
}

// k0 from ub = maxL[n-1]: keep strips with STRIP_COST*(n-1-k) <= ub (distances
// >= 0 make this sufficient; 1e-3 margin => rounding can only KEEP extra strips,
// never drop a tied one -> exact). g clamped to [0,127] defensively.
__device__ __forceinline__ int k0_from_ub(float ub, int n) {
    int g = (int)(ub * (1.0f / STRIP_COST) + 1e-3f);
    if (g < 0) g = 0;
    if (g > NSTRIP - 1) g = NSTRIP - 1;
    int k0 = n - 1 - g;
    return (k0 < 0) ? 0 : k0;
}

// =====================================================================================
// Fused kernel: all 3 strip phases + final reduce in ONE dispatch.
// Co-residency by construction: __launch_bounds__(64,2) caps VGPR at 256; any
// VGPR<=256 gives >=2 waves/SIMD -> >=8 single-wave blocks/CU -> >=2048 slots =
// grid size (LDS 8KB -> 20/CU, not binding) => waits cannot deadlock (deps form
// a DAG over strips). (64,4) forbidden: VGPR->64, ~90MB scratch spill (round 3).
// =====================================================================================
__global__ __launch_bounds__(64, 2) void fused_kernel(
        const float* __restrict__ pred, const int* __restrict__ tg,
        const float* __restrict__ lv, float* __restrict__ out,
        float* __restrict__ Llast, float* __restrict__ mmax1, int* __restrict__ blkflags,
        float* __restrict__ Llast2, float* __restrict__ mmax2, float* __restrict__ sacc,
        int* f1, int* f2, int* f3) {
    const int s = blockIdx.x >> 7, sig = blockIdx.x & 127;
    const int lane = threadIdx.x;
    const int c0 = lane * 8;
    const int* tgb = tg + (size_t)s * NPIX;
    const int R0 = sig * TST;
    const int base = s * NSTRIP;
    float jc[8];
#pragma unroll
    for (int i = 0; i < 8; ++i) jc[i] = A_W * (float)(c0 + i);

    __shared__ float lds[TST][WDIM];   // 8 KB; single-wave block

    // ---------------- phase 1: local strip scan (INF incoming) -> Llast/mmax1/flags
    unsigned int smaskp = 0u, rawbgp = 0u;   // byte t = row t's 8-bit masks
    RowBits rA = loadrow_bits(tgb, R0 - 1, c0);
    RowBits rB = loadrow_bits(tgb, R0, c0);
    float prev[8];
#pragma unroll
    for (int i = 0; i < 8; ++i) prev[i] = INF_W;
    int fgor = 0, bgor = 0;
#pragma unroll
    for (int t = 0; t < TST; ++t) {
        RowBits rC = loadrow_bits(tgb, R0 + t + 1, c0);
        fgor |= (~rB.rawbg) & 0xFF;
        bgor |= rB.rawbg;
        int smask = (rA.efg | rB.efg | rC.efg) & (rA.ebg | rB.ebg | rC.ebg);
        smaskp |= ((unsigned int)smask) << (8 * t);
        rawbgp |= ((unsigned int)rB.rawbg) << (8 * t);
        float dr[8];
#pragma unroll
        for (int i = 0; i < 8; ++i) dr[i] = ((smask >> i) & 1) ? 0.f : INF_W;
        row_step(jc, prev, dr);
        rA = rB; rB = rC;
    }
    {
        float* Lr = Llast + ((size_t)base + sig) * WDIM + c0;
        f32x4 v0 = {prev[0], prev[1], prev[2], prev[3]};
        f32x4 v1 = {prev[4], prev[5], prev[6], prev[7]};
        st_wt4(Lr, v0);
        st_wt4(Lr + 4, v1);
        store_max(prev, mmax1, base + sig, lane);
        int wf = __any(fgor != 0) ? 1 : 0;
        int wb = __any(bgor != 0) ? 2 : 0;
        if (lane == 0) st_wti(&blkflags[blockIdx.x], wf | wb);
    }
    flag_post(&f1[base + sig], lane);

    // ---------------- phase 2: exact pass-1 rows -> LDS; flipped local scan -> Llast2/mmax2
    if (sig == 0) {
#pragma unroll
        for (int i = 0; i < 8; ++i) prev[i] = INF_W;
    } else {
        wait_flag(&f1[base + sig - 1]);
        float ub = ld_bp(&mmax1[base + sig - 1]);
        int k0 = k0_from_ub(ub, sig);
        wait_flags_range(f1 + base, k0, sig - 1, lane);
        chain_walk(Llast + (size_t)base * WDIM, k0, sig, jc, c0, prev);
    }
#pragma unroll
    for (int t = 0; t < TST; ++t) {
        unsigned int sm = (smaskp >> (8 * t)) & 0xFFu;
        float dr[8];
#pragma unroll
        for (int i = 0; i < 8; ++i) dr[i] = ((sm >> i) & 1u) ? 0.f : INF_W;
        row_step(jc, prev, dr);
        *(float4*)&lds[t][c0]     = make_float4(prev[0], prev[1], prev[2], prev[3]);
        *(float4*)&lds[t][c0 + 4] = make_float4(prev[4], prev[5], prev[6], prev[7]);
    }
    __syncthreads();
    // flipped (pass-2) local scan over this strip, INF incoming
#pragma unroll
    for (int i = 0; i < 8; ++i) prev[i] = INF_W;
#pragma unroll
    for (int t2 = 0; t2 < TST; ++t2) {
        float4 a = *(const float4*)&lds[TST - 1 - t2][504 - c0];
        float4 q = *(const float4*)&lds[TST - 1 - t2][508 - c0];
        float dr[8];
        dr[7]=a.x; dr[6]=a.y; dr[5]=a.z; dr[4]=a.w;
        dr[3]=q.x; dr[2]=q.y; dr[1]=q.z; dr[0]=q.w;
        row_step(jc, prev, dr);
    }
    const int sig2 = NSTRIP - 1 - sig;   // flipped strip index == this block's own rows
    {
        float* Lr = Llast2 + ((size_t)base + sig2) * WDIM + c0;
        f32x4 v0 = {prev[0], prev[1], prev[2], prev[3]};
        f32x4 v1 = {prev[4], prev[5], prev[6], prev[7]};
        st_wt4(Lr, v0);
        st_wt4(Lr + 4, v1);
        store_max(prev, mmax2, base + sig2, lane);
    }
    flag_post(&f2[base + sig2], lane);

    // ---------------- phase 3: exact pass-2 rows (dr from own LDS) + fused loss -> sacc
    if (sig2 == 0) {
#pragma unroll
        for (int i = 0; i < 8; ++i) prev[i] = INF_W;
    } else {
        wait_flag(&f2[base + sig2 - 1]);
        float ub = ld_bp(&mmax2[base + sig2 - 1]);
        int k0 = k0_from_ub(ub, sig2);
        wait_flags_range(f2 + base, k0, sig2 - 1, lane);
        chain_walk(Llast2 + (size_t)base * WDIM, k0, sig2, jc, c0, prev);
    }
    const size_t sb = (size_t)s * NPIX;
    float mx = 0.f, facc = 0.f, s1 = 0.f, s2 = 0.f, iacc = 0.f, pacc = 0.f;
#pragma unroll
    for (int t = 0; t < TST; ++t) {
        const int pr = R0 + (TST - 1) - t;        // == HDIM-1-(sig2*TST+t), own strip rows
        float4 a  = *(const float4*)&lds[TST - 1 - t][504 - c0];
        float4 b4 = *(const float4*)&lds[TST - 1 - t][508 - c0];
        float dr[8];
        dr[7]=a.x;  dr[6]=a.y;  dr[5]=a.z;  dr[4]=a.w;
        dr[3]=b4.x; dr[2]=b4.y; dr[1]=b4.z; dr[0]=b4.w;
        const size_t rbase = sb + (size_t)pr * WDIM + (WDIM - 8 - c0);
        float4 xa = *(const float4*)(pred + rbase);
        float4 xb = *(const float4*)(pred + rbase + 4);
        float px[8];
        px[7]=xa.x; px[6]=xa.y; px[5]=xa.z; px[4]=xa.w;
        px[3]=xb.x; px[2]=xb.y; px[1]=xb.z; px[0]=xb.w;
        // target bits for reversed columns: col 511-c0-i lives in lane 63-lane, bit 7-i
        int sh = __shfl((int)((rawbgp >> (8 * (TST - 1 - t))) & 0xFFu), 63 - lane);
        row_step(jc, prev, dr);
#pragma unroll
        for (int i = 0; i < 8; ++i) {
            float x = px[i];
            float dd = prev[i];
            float e = __expf(-fabsf(x));
            float inv = 1.f / (1.f + e);
            float pr_ = (x >= 0.f) ? inv : (1.f - inv);   // sigmoid(x)
            float L = __logf(1.f + e);                    // softplus(-|x|)
            bool t1 = ((sh >> (7 - i)) & 1) == 0;         // fg pixel
            float fo = t1 ? 0.25f * (1.f - pr_) * (1.f - pr_) * (fmaxf(-x, 0.f) + L)
                          : 0.75f * pr_ * pr_ * (fmaxf(x, 0.f) + L);
            facc += fo;
            float base_ = t1 ? (1.f - pr_) : pr_;
            s1 += base_;
            s2 += base_ * dd;
            float tf = t1 ? 1.f : 0.f;
            iacc += tf * pr_;
            pacc += pr_ + tf;
            mx = fmaxf(mx, dd);
        }
    }
#pragma unroll
    for (int off = 32; off > 0; off >>= 1) {
        facc += __shfl_xor(facc, off);
        s1   += __shfl_xor(s1, off);
        s2   += __shfl_xor(s2, off);
        iacc += __shfl_xor(iacc, off);
        pacc += __shfl_xor(pacc, off);
        mx    = fmaxf(mx, __shfl_xor(mx, off));
    }
    if (lane == 0) {
        const int idx = base + sig2;
        st_wt(&sacc[0 * NBLK + idx], s1);
        st_wt(&sacc[1 * NBLK + idx], s2);
        st_wt(&sacc[2 * NBLK + idx], iacc);
        st_wt(&sacc[3 * NBLK + idx], pacc);
        st_wt(&sacc[4 * NBLK + idx], mx);
        st_wt(&sacc[5 * NBLK + idx], facc);
    }
    flag_post(&f3[blockIdx.x], lane);

    // ---------------- phase 4: final reduction in block 0 only
    if (blockIdx.x != 0) return;
    for (;;) {
        int ok = 1;
#pragma unroll
        for (int w = 0; w < 32; ++w) ok &= (ld_bpi(&f3[w * 64 + lane]) != 0);
        if (__all(ok)) break;
        __builtin_amdgcn_s_sleep(8);
    }
    asm volatile("" ::: "memory");
    float fsum = 0.f, bsum = 0.f, dsum = 0.f, isum = 0.f;
    for (int ss = 0; ss < NSAMP; ++ss) {
        int i0 = ss * NSTRIP + lane, i1 = i0 + 64;
        float t1 = ld_bp(&sacc[0 * NBLK + i0]) + ld_bp(&sacc[0 * NBLK + i1]);
        float t2 = ld_bp(&sacc[1 * NBLK + i0]) + ld_bp(&sacc[1 * NBLK + i1]);
        float ia = ld_bp(&sacc[2 * NBLK + i0]) + ld_bp(&sacc[2 * NBLK + i1]);
        float pa = ld_bp(&sacc[3 * NBLK + i0]) + ld_bp(&sacc[3 * NBLK + i1]);
        float mxs = fmaxf(ld_bp(&sacc[4 * NBLK + i0]), ld_bp(&sacc[4 * NBLK + i1]));
        float fa = ld_bp(&sacc[5 * NBLK + i0]) + ld_bp(&sacc[5 * NBLK + i1]);
        int   vv = ld_bpi(&blkflags[i0]) | ld_bpi(&blkflags[i1]);
#pragma unroll
        for (int off = 32; off > 0; off >>= 1) {
            t1 += __shfl_xor(t1, off);
            t2 += __shfl_xor(t2, off);
            ia += __shfl_xor(ia, off);
            pa += __shfl_xor(pa, off);
            fa += __shfl_xor(fa, off);
            mxs = fmaxf(mxs, __shfl_xor(mxs, off));
            vv |= __shfl_xor(vv, off);
        }
        bool hasb = (vv & 3) == 3;     // boundary nonempty (has_fg && has_bg)
        fsum += fa;
        float distsum = hasb ? ((mxs > 0.f) ? t2 / fmaxf(mxs, 1e-12f) : 0.f) : t1;
        bsum += t1 + distsum;
        dsum += (2.f * ia + 1e-6f) / (pa + 1e-6f);
        isum += (ia + 1e-6f) / (pa - ia + 1e-6f);
    }
    if (lane == 0) {
        float focal = fsum / NTOT_F;
        float bnd   = bsum / NTOT_F;
        float dice = 1.f - dsum / 16.f;
        float iou  = 1.f - isum / 16.f;
        float l0 = lv[0], l1 = lv[1], l2 = lv[2], l3 = lv[3];
        float total = expf(-l0) * focal + l0 + expf(-l1) * dice + l1
                    + expf(-l2) * bnd  + l2 + expf(-l3) * iou  + l3;
        out[0] = total; out[1] = focal; out[2] = dice; out[3] = bnd; out[4] = iou;
    }
}

extern "C" void kernel_launch(void* const* d_in, const int* in_sizes, int n_in,
                              void* d_out, int out_size, void* d_ws, size_t ws_size,
                              hipStream_t stream) {
    const float* pred = (const float*)d_in[0];
    const int*   tg   = (const int*)d_in[1];
    const float* lv   = (const float*)d_in[2];
    float* out = (float*)d_out;
    char* ws = (char*)d_ws;
    int*   f1       = (int*)(ws + OFF_F1);
    int*   f2       = (int*)(ws + OFF_F2);
    int*   f3       = (int*)(ws + OFF_F3);
    int*   blkflags = (int*)(ws + OFF_FLAGS);
    float* sacc     = (float*)(ws + OFF_SACC);
    float* mmax1    = (float*)(ws + OFF_MMAX1);
    float* mmax2    = (float*)(ws + OFF_MMAX2);
    float* Llast    = (float*)(ws + OFF_LLAST);
    float* Llast2   = (float*)(ws + OFF_LLAST2);

    // ws is poisoned between iterations -> flags must be zeroed each launch.
    hipMemsetAsync(ws, 0, 24576, stream);
    fused_kernel<<<NBLK, 64, 0, stream>>>(pred, tg, lv, out, Llast, mmax1, blkflags,
                                          Llast2, mmax2, sacc, f1, f2, f3);
}

// Round 11
// 101.185 us; speedup vs baseline: 5.4751x; 1.1068x over previous
//
#include <hip/hip_runtime.h>
#include <math.h>

#define A_W 0.955f
#define B_W 1.3693f
#define INF_W 1e6f
#define HDIM 512
#define WDIM 512
#define NPIX (HDIM*WDIM)
#define NSAMP 16
#define NTOT_F 4194304.0f
#define TST 4        // strip height
#define NSTRIP 128   // strips per sample
#define NBLK (NSAMP*NSTRIP)        // 2048
#define STRIP_COST (4.0f * A_W)    // min cost to propagate a boundary through one strip

// ws layout (bytes):
//  [0,8192):        int f1[2048]    (phase-1 done flags, per strip)       [cleared]
//  [8192,16384):    int f2[2048]    (phase-2 done flags, per flipped strip)[cleared]
//  [16384,24576):   int f3[2048]    (phase-3 done flags)                  [cleared]
//  [24576,24704):   int f4[16]+pad  (per-sample phase-4a done flags)      [cleared]
//  [32768,81920):   float sacc[6][2048]
//  [81920,90112):   float mmax1[2048]   (max of Llast rows)
//  [90112,98304):   float mmax2[2048]   (max of Llast2 rows)
//  [98304,106496):  int blkflags[2048]  (bit0=has_fg,bit1=has_bg; fully rewritten)
//  [106496,106880): float sacc2[6][16]  (per-sample partials)
//  [106880,106944): int vv2[16]         (per-sample blkflag OR)
//  [1MB,5MB):       float Llast[16][128][512]
//  [5MB,9MB):       float Llast2[16][128][512]
#define OFF_F1     0
#define OFF_F2     8192
#define OFF_F3     16384
#define OFF_F4     24576
#define OFF_SACC   32768
#define OFF_MMAX1  81920
#define OFF_MMAX2  90112
#define OFF_FLAGS  98304
#define OFF_SACC2  106496
#define OFF_VV2    106880
#define OFF_LLAST  (1u<<20)
#define OFF_LLAST2 (5u<<20)

typedef float f32x4 __attribute__((ext_vector_type(4)));

// ---- fence-free cross-block data movement --------------------------------------
// gfx950 XCD L2s are non-coherent; agent-scope ACQ/REL atomics emit whole-L2
// writeback/invalidate (round 4: ~420us floor). Proven scheme (rounds 5/6/8/10):
// payload via L1+L2-BYPASS ops (-> MALL, common point); producer drains with
// s_waitcnt vmcnt(0); SIGNAL = RELAXED ATOMIC RMW on a distinct per-strip flag
// (plain-store signal broke visibility in round 7; hot-line RMWs serialized in
// round 6 — both are known regressions, do not revisit).
// ROUND-9 LESSON: compiler-tracked prefetch loads held across the untracked
// inline-asm load region (chain_walk) broke correctness. One change per round.
__device__ __forceinline__ void st_wti(int* p, int v) {
    __hip_atomic_store(p, v, __ATOMIC_RELAXED, __HIP_MEMORY_SCOPE_AGENT);
}
__device__ __forceinline__ int ld_bpi(const int* p) {
    return __hip_atomic_load((int*)p, __ATOMIC_RELAXED, __HIP_MEMORY_SCOPE_AGENT);
}
__device__ __forceinline__ void st_wt(float* p, float v) {
    st_wti((int*)p, __float_as_int(v));
}
__device__ __forceinline__ float ld_bp(const float* p) {
    return __int_as_float(ld_bpi((const int*)p));
}
// 16B-wide L1+L2-bypass ops. "=&v" early-clobber: dest must not overlap the
// address pair. Results readable only after vm_wait0().
__device__ __forceinline__ f32x4 ld_bp4(const float* p) {
    f32x4 r;
    asm volatile("global_load_dwordx4 %0, %1, off sc0 sc1"
                 : "=&v"(r) : "v"(p) : "memory");
    return r;
}
__device__ __forceinline__ void st_wt4(float* p, f32x4 v) {
    asm volatile("global_store_dwordx4 %0, %1, off sc0 sc1"
                 :: "v"(p), "v"(v) : "memory");
}
__device__ __forceinline__ void vm_wait0() {
    asm volatile("s_waitcnt vmcnt(0)" ::: "memory");
    __builtin_amdgcn_sched_barrier(0);   // block reg-only hoisting past the wait
}

// Publish: drain this wave's write-through stores to MALL (vmcnt is wave-level,
// covers all 64 lanes), then bump the flag with a relaxed RMW.
__device__ __forceinline__ void flag_post(int* f, int lane) {
    asm volatile("s_waitcnt vmcnt(0)" ::: "memory");
    if (lane == 0)
        __hip_atomic_fetch_add(f, 1, __ATOMIC_RELAXED, __HIP_MEMORY_SCOPE_AGENT);
}
__device__ __forceinline__ void wait_flag(const int* f) {
    while (!__all(ld_bpi(f) != 0))
        __builtin_amdgcn_s_sleep(2);
    asm volatile("" ::: "memory");   // no payload reads hoisted above the spin
}
// wait until f[k] != 0 for all k in [k0, kend); kend-k0 <= 128
__device__ __forceinline__ void wait_flags_range(const int* f, int k0, int kend,
                                                 int lane) {
    if (k0 >= kend) return;
    for (;;) {
        int k1 = k0 + lane, k2 = k0 + 64 + lane;
        int v1 = (k1 < kend) ? ld_bpi(&f[k1]) : 1;
        int v2 = (k2 < kend) ? ld_bpi(&f[k2]) : 1;
        if (__all((v1 != 0) & (v2 != 0))) break;
        __builtin_amdgcn_s_sleep(2);
    }
    asm volatile("" ::: "memory");
}

// DPP move with INF fill (floats).
template<int CTRL, int RMASK>
__device__ __forceinline__ float dpp_mov_inf(float x) {
    return __int_as_float(__builtin_amdgcn_update_dpp(
        __float_as_int(INF_W), __float_as_int(x), CTRL, RMASK, 0xF, false));
}
template<int CTRL>
__device__ __forceinline__ int dpp_mov0_i(int x) {
    return __builtin_amdgcn_update_dpp(0, x, CTRL, 0xF, 0xF, true);
}

__device__ __forceinline__ float wave_prefix_min_incl(float t) {
    t = fminf(t, dpp_mov_inf<0x111,0xF>(t));
    t = fminf(t, dpp_mov_inf<0x112,0xF>(t));
    t = fminf(t, dpp_mov_inf<0x114,0xF>(t));
    t = fminf(t, dpp_mov_inf<0x118,0xF>(t));
    t = fminf(t, dpp_mov_inf<0x142,0xA>(t));
    t = fminf(t, dpp_mov_inf<0x143,0xC>(t));
    return t;
}

__device__ __forceinline__ void cummin_row(const float* jc, float* v) {
    float g[8];
#pragma unroll
    for (int i = 0; i < 8; ++i) g[i] = v[i] - jc[i];
    float c1[8];
    c1[0] = g[0];
#pragma unroll
    for (int i = 1; i < 8; ++i) c1[i] = fminf(g[i], g[i-1]);
    float c2[8];
    c2[0] = c1[0]; c2[1] = c1[1];
#pragma unroll
    for (int i = 2; i < 8; ++i) c2[i] = fminf(c1[i], c1[i-2]);
    float cj[8];
    cj[0] = c2[0]; cj[1] = c2[1]; cj[2] = c2[2]; cj[3] = c2[3];
#pragma unroll
    for (int i = 4; i < 8; ++i) cj[i] = fminf(c2[i], c2[i-4]);
    float t  = wave_prefix_min_incl(cj[7]);
    float ex = dpp_mov_inf<0x138,0xF>(t);
#pragma unroll
    for (int i = 0; i < 8; ++i) v[i] = jc[i] + fminf(cj[i], ex);
}

__device__ __forceinline__ void row_step(const float* jc, float* prev, const float* drow) {
    float lIn = dpp_mov_inf<0x138,0xF>(prev[7]);
    float rIn = dpp_mov_inf<0x130,0xF>(prev[0]);
    float m[8];
#pragma unroll
    for (int i = 0; i < 8; ++i) {
        float up = prev[i] + A_W;
        float ul = ((i == 0) ? lIn : prev[i-1]) + B_W;
        float ur = ((i == 7) ? rIn : prev[i+1]) + B_W;
        m[i] = fminf(fminf(drow[i], up), fminf(ul, ur));
    }
    cummin_row(jc, m);
#pragma unroll
    for (int i = 0; i < 8; ++i) prev[i] = m[i];
}

// 4 fused T3 steps (exact, INF outside grid). T3^4 == one call (TST==4).
__device__ __forceinline__ void t3x4(float* b) {
    float e[16];
#pragma unroll
    for (int k = 0; k < 4; ++k) e[k]    = dpp_mov_inf<0x138,0xF>(b[4+k]);
#pragma unroll
    for (int k = 0; k < 8; ++k) e[4+k]  = b[k];
#pragma unroll
    for (int k = 0; k < 4; ++k) e[12+k] = dpp_mov_inf<0x130,0xF>(b[k]);
    const float w0 = 4.f*A_W, w1 = 3.f*A_W + B_W, w2 = 2.f*A_W + 2.f*B_W;
    const float w3 = A_W + 3.f*B_W, w4 = 4.f*B_W;
#pragma unroll
    for (int i = 0; i < 8; ++i) {
        float m = e[i+4] + w0;
        m = fminf(m, fminf(e[i+3], e[i+5]) + w1);
        m = fminf(m, fminf(e[i+2], e[i+6]) + w2);
        m = fminf(m, fminf(e[i+1], e[i+7]) + w3);
        m = fminf(m, fminf(e[i+0], e[i+8]) + w4);
        b[i] = m;
    }
}

struct RowBits { int efg; int ebg; int rawbg; };

__device__ __forceinline__ RowBits make_rowbits(uint4 a, uint4 b) {
    int fg = ((a.x!=0u)?1:0) | ((a.y!=0u)?2:0) | ((a.z!=0u)?4:0) | ((a.w!=0u)?8:0)
           | ((b.x!=0u)?16:0) | ((b.y!=0u)?32:0) | ((b.z!=0u)?64:0) | ((b.w!=0u)?128:0);
    int bg = (~fg) & 0xFF;
    int lf = dpp_mov0_i<0x138>(fg), rf = dpp_mov0_i<0x130>(fg);
    int lb = dpp_mov0_i<0x138>(bg), rb = dpp_mov0_i<0x130>(bg);
    RowBits r;
    r.efg = (fg | (fg<<1) | (fg>>1) | ((lf>>7)&1) | ((rf&1)<<7)) & 0xFF;
    r.ebg = (bg | (bg<<1) | (bg>>1) | ((lb>>7)&1) | ((rb&1)<<7)) & 0xFF;
    r.rawbg = bg;
    return r;
}

__device__ __forceinline__ RowBits loadrow_bits(const int* tgb, int rr, int c0) {
    if (rr < 0 || rr >= HDIM) { RowBits z; z.efg = 0; z.ebg = 0; z.rawbg = 0; return z; }
    const uint4* p = (const uint4*)(tgb + (size_t)rr * WDIM + c0);
    return make_rowbits(p[0], p[1]);
}

// store max of an L row (prev[8] across wave) into mmax (write-through)
__device__ __forceinline__ void store_max(const float* prev, float* __restrict__ mmax,
                                          int idx, int lane) {
    float mx = prev[0];
#pragma unroll
    for (int i = 1; i < 8; ++i) mx = fmaxf(mx, prev[i]);
#pragma unroll
    for (int off = 32; off > 0; off >>= 1) mx = fmaxf(mx, __shfl_xor(mx, off));
    if (lane == 0) st_wt(&mmax[idx], mx);
}

// Exact boundary via chain walk over strips [k0, n-1]. Caller guarantees flags
// [k0, n-1] observed. 16B bypass loads issued before t3x4/cummin to hide MALL
// latency; results consumed only after vm_wait0().
__device__ __forceinline__ void chain_walk(const float* __restrict__ Lb, int k0, int n,
                                           const float* jc, int c0, float* prev) {
    float b[8];
    const float* Lr = Lb + (size_t)k0 * WDIM + c0;
    f32x4 l0 = ld_bp4(Lr);
    f32x4 l1 = ld_bp4(Lr + 4);
    vm_wait0();
#pragma unroll
    for (int i = 0; i < 4; ++i) { b[i] = l0[i]; b[4 + i] = l1[i]; }
    for (int sg = k0 + 1; sg < n; ++sg) {
        const float* Ls = Lb + (size_t)sg * WDIM + c0;
        f32x4 m0 = ld_bp4(Ls);
        f32x4 m1 = ld_bp4(Ls + 4);
        t3x4(b);                                 // T3^4 exact (TST==4)
        cummin_row(jc, b);
        vm_wait0();
#pragma unroll
        for (int i = 0; i < 4; ++i) {
            b[i]     = fminf(b[i],     m0[i]);
            b[4 + i] = fminf(b[4 + i], m1[i]);
        }
    }
#pragma unroll
    for (int i = 0; i < 8; ++i) prev[i] = b[i];
}

// k0 from ub = maxL[n-1]: keep strips with STRIP_COST*(n-1-k) <= ub (distances
// >= 0 make this sufficient; 1e-3 margin => rounding can only KEEP extra strips,
// never drop a tied one -> exact). g clamped to [0,127] defensively.
__device__ __forceinline__ int k0_from_ub(float ub, int n) {
    int g = (int)(ub * (1.0f / STRIP_COST) + 1e-3f);
    if (g < 0) g = 0;
    if (g > NSTRIP - 1) g = NSTRIP - 1;
    int k0 = n - 1 - g;
    return (k0 < 0) ? 0 : k0;
}

// =====================================================================================
// Fused kernel: all 3 strip phases + two-level final reduce in ONE dispatch.
// Co-residency by construction: __launch_bounds__(64,2) caps VGPR at 256; any
// VGPR<=256 gives >=2 waves/SIMD -> >=8 single-wave blocks/CU -> >=2048 slots =
// grid size (LDS 8KB -> 20/CU, not binding) => waits cannot deadlock (deps form
// a DAG over strips). (64,4) forbidden: VGPR->64, ~90MB scratch spill (round 3).
// Round-11 change (ONE change): phase 4 split into 4a (per-sample reduce in each
// sample's sig==0 block; polls only 128 f3 flags) + 4b (block 0 combines 16
// partials) — removes the 2048-flag poll + 16x13-load serial tail from block 0.
// =====================================================================================
__global__ __launch_bounds__(64, 2) void fused_kernel(
        const float* __restrict__ pred, const int* __restrict__ tg,
        const float* __restrict__ lv, float* __restrict__ out,
        float* __restrict__ Llast, float* __restrict__ mmax1, int* __restrict__ blkflags,
        float* __restrict__ Llast2, float* __restrict__ mmax2, float* __restrict__ sacc,
        int* f1, int* f2, int* f3, int* f4,
        float* __restrict__ sacc2, int* __restrict__ vv2) {
    const int s = blockIdx.x >> 7, sig = blockIdx.x & 127;
    const int lane = threadIdx.x;
    const int c0 = lane * 8;
    const int* tgb = tg + (size_t)s * NPIX;
    const int R0 = sig * TST;
    const int base = s * NSTRIP;
    float jc[8];
#pragma unroll
    for (int i = 0; i < 8; ++i) jc[i] = A_W * (float)(c0 + i);

    __shared__ float lds[TST][WDIM];   // 8 KB; single-wave block

    // ---------------- phase 1: local strip scan (INF incoming) -> Llast/mmax1/flags
    unsigned int smaskp = 0u, rawbgp = 0u;   // byte t = row t's 8-bit masks
    RowBits rA = loadrow_bits(tgb, R0 - 1, c0);
    RowBits rB = loadrow_bits(tgb, R0, c0);
    float prev[8];
#pragma unroll
    for (int i = 0; i < 8; ++i) prev[i] = INF_W;
    int fgor = 0, bgor = 0;
#pragma unroll
    for (int t = 0; t < TST; ++t) {
        RowBits rC = loadrow_bits(tgb, R0 + t + 1, c0);
        fgor |= (~rB.rawbg) & 0xFF;
        bgor |= rB.rawbg;
        int smask = (rA.efg | rB.efg | rC.efg) & (rA.ebg | rB.ebg | rC.ebg);
        smaskp |= ((unsigned int)smask) << (8 * t);
        rawbgp |= ((unsigned int)rB.rawbg) << (8 * t);
        float dr[8];
#pragma unroll
        for (int i = 0; i < 8; ++i) dr[i] = ((smask >> i) & 1) ? 0.f : INF_W;
        row_step(jc, prev, dr);
        rA = rB; rB = rC;
    }
    {
        float* Lr = Llast + ((size_t)base + sig) * WDIM + c0;
        f32x4 v0 = {prev[0], prev[1], prev[2], prev[3]};
        f32x4 v1 = {prev[4], prev[5], prev[6], prev[7]};
        st_wt4(Lr, v0);
        st_wt4(Lr + 4, v1);
        store_max(prev, mmax1, base + sig, lane);
        int wf = __any(fgor != 0) ? 1 : 0;
        int wb = __any(bgor != 0) ? 2 : 0;
        if (lane == 0) st_wti(&blkflags[blockIdx.x], wf | wb);
    }
    flag_post(&f1[base + sig], lane);

    // ---------------- phase 2: exact pass-1 rows -> LDS; flipped local scan -> Llast2/mmax2
    if (sig == 0) {
#pragma unroll
        for (int i = 0; i < 8; ++i) prev[i] = INF_W;
    } else {
        wait_flag(&f1[base + sig - 1]);
        float ub = ld_bp(&mmax1[base + sig - 1]);
        int k0 = k0_from_ub(ub, sig);
        wait_flags_range(f1 + base, k0, sig - 1, lane);
        chain_walk(Llast + (size_t)base * WDIM, k0, sig, jc, c0, prev);
    }
#pragma unroll
    for (int t = 0; t < TST; ++t) {
        unsigned int sm = (smaskp >> (8 * t)) & 0xFFu;
        float dr[8];
#pragma unroll
        for (int i = 0; i < 8; ++i) dr[i] = ((sm >> i) & 1u) ? 0.f : INF_W;
        row_step(jc, prev, dr);
        *(float4*)&lds[t][c0]     = make_float4(prev[0], prev[1], prev[2], prev[3]);
        *(float4*)&lds[t][c0 + 4] = make_float4(prev[4], prev[5], prev[6], prev[7]);
    }
    __syncthreads();
    // flipped (pass-2) local scan over this strip, INF incoming
#pragma unroll
    for (int i = 0; i < 8; ++i) prev[i] = INF_W;
#pragma unroll
    for (int t2 = 0; t2 < TST; ++t2) {
        float4 a = *(const float4*)&lds[TST - 1 - t2][504 - c0];
        float4 q = *(const float4*)&lds[TST - 1 - t2][508 - c0];
        float dr[8];
        dr[7]=a.x; dr[6]=a.y; dr[5]=a.z; dr[4]=a.w;
        dr[3]=q.x; dr[2]=q.y; dr[1]=q.z; dr[0]=q.w;
        row_step(jc, prev, dr);
    }
    const int sig2 = NSTRIP - 1 - sig;   // flipped strip index == this block's own rows
    {
        float* Lr = Llast2 + ((size_t)base + sig2) * WDIM + c0;
        f32x4 v0 = {prev[0], prev[1], prev[2], prev[3]};
        f32x4 v1 = {prev[4], prev[5], prev[6], prev[7]};
        st_wt4(Lr, v0);
        st_wt4(Lr + 4, v1);
        store_max(prev, mmax2, base + sig2, lane);
    }
    flag_post(&f2[base + sig2], lane);

    // ---------------- phase 3: exact pass-2 rows (dr from own LDS) + fused loss -> sacc
    if (sig2 == 0) {
#pragma unroll
        for (int i = 0; i < 8; ++i) prev[i] = INF_W;
    } else {
        wait_flag(&f2[base + sig2 - 1]);
        float ub = ld_bp(&mmax2[base + sig2 - 1]);
        int k0 = k0_from_ub(ub, sig2);
        wait_flags_range(f2 + base, k0, sig2 - 1, lane);
        chain_walk(Llast2 + (size_t)base * WDIM, k0, sig2, jc, c0, prev);
    }
    const size_t sb = (size_t)s * NPIX;
    float mx = 0.f, facc = 0.f, s1 = 0.f, s2 = 0.f, iacc = 0.f, pacc = 0.f;
#pragma unroll
    for (int t = 0; t < TST; ++t) {
        const int pr = R0 + (TST - 1) - t;        // == HDIM-1-(sig2*TST+t), own strip rows
        float4 a  = *(const float4*)&lds[TST - 1 - t][504 - c0];
        float4 b4 = *(const float4*)&lds[TST - 1 - t][508 - c0];
        float dr[8];
        dr[7]=a.x;  dr[6]=a.y;  dr[5]=a.z;  dr[4]=a.w;
        dr[3]=b4.x; dr[2]=b4.y; dr[1]=b4.z; dr[0]=b4.w;
        const size_t rbase = sb + (size_t)pr * WDIM + (WDIM - 8 - c0);
        float4 xa = *(const float4*)(pred + rbase);
        float4 xb = *(const float4*)(pred + rbase + 4);
        float px[8];
        px[7]=xa.x; px[6]=xa.y; px[5]=xa.z; px[4]=xa.w;
        px[3]=xb.x; px[2]=xb.y; px[1]=xb.z; px[0]=xb.w;
        // target bits for reversed columns: col 511-c0-i lives in lane 63-lane, bit 7-i
        int sh = __shfl((int)((rawbgp >> (8 * (TST - 1 - t))) & 0xFFu), 63 - lane);
        row_step(jc, prev, dr);
#pragma unroll
        for (int i = 0; i < 8; ++i) {
            float x = px[i];
            float dd = prev[i];
            float e = __expf(-fabsf(x));
            float inv = 1.f / (1.f + e);
            float pr_ = (x >= 0.f) ? inv : (1.f - inv);   // sigmoid(x)
            float L = __logf(1.f + e);                    // softplus(-|x|)
            bool t1 = ((sh >> (7 - i)) & 1) == 0;         // fg pixel
            float fo = t1 ? 0.25f * (1.f - pr_) * (1.f - pr_) * (fmaxf(-x, 0.f) + L)
                          : 0.75f * pr_ * pr_ * (fmaxf(x, 0.f) + L);
            facc += fo;
            float base_ = t1 ? (1.f - pr_) : pr_;
            s1 += base_;
            s2 += base_ * dd;
            float tf = t1 ? 1.f : 0.f;
            iacc += tf * pr_;
            pacc += pr_ + tf;
            mx = fmaxf(mx, dd);
        }
    }
#pragma unroll
    for (int off = 32; off > 0; off >>= 1) {
        facc += __shfl_xor(facc, off);
        s1   += __shfl_xor(s1, off);
        s2   += __shfl_xor(s2, off);
        iacc += __shfl_xor(iacc, off);
        pacc += __shfl_xor(pacc, off);
        mx    = fmaxf(mx, __shfl_xor(mx, off));
    }
    if (lane == 0) {
        const int idx = base + sig2;
        st_wt(&sacc[0 * NBLK + idx], s1);
        st_wt(&sacc[1 * NBLK + idx], s2);
        st_wt(&sacc[2 * NBLK + idx], iacc);
        st_wt(&sacc[3 * NBLK + idx], pacc);
        st_wt(&sacc[4 * NBLK + idx], mx);
        st_wt(&sacc[5 * NBLK + idx], facc);
    }
    flag_post(&f3[blockIdx.x], lane);

    // ---------------- phase 4a: per-sample reduce in each sample's sig==0 block
    if (sig != 0) return;
    wait_flags_range(f3, base, base + NSTRIP, lane);
    {
        int i0 = base + lane, i1 = i0 + 64;
        float t1 = ld_bp(&sacc[0 * NBLK + i0]) + ld_bp(&sacc[0 * NBLK + i1]);
        float t2 = ld_bp(&sacc[1 * NBLK + i0]) + ld_bp(&sacc[1 * NBLK + i1]);
        float ia = ld_bp(&sacc[2 * NBLK + i0]) + ld_bp(&sacc[2 * NBLK + i1]);
        float pa = ld_bp(&sacc[3 * NBLK + i0]) + ld_bp(&sacc[3 * NBLK + i1]);
        float mxs = fmaxf(ld_bp(&sacc[4 * NBLK + i0]), ld_bp(&sacc[4 * NBLK + i1]));
        float fa = ld_bp(&sacc[5 * NBLK + i0]) + ld_bp(&sacc[5 * NBLK + i1]);
        int   vv = ld_bpi(&blkflags[i0]) | ld_bpi(&blkflags[i1]);
#pragma unroll
        for (int off = 32; off > 0; off >>= 1) {
            t1 += __shfl_xor(t1, off);
            t2 += __shfl_xor(t2, off);
            ia += __shfl_xor(ia, off);
            pa += __shfl_xor(pa, off);
            fa += __shfl_xor(fa, off);
            mxs = fmaxf(mxs, __shfl_xor(mxs, off));
            vv |= __shfl_xor(vv, off);
        }
        if (lane == 0) {
            st_wt(&sacc2[0 * 16 + s], t1);
            st_wt(&sacc2[1 * 16 + s], t2);
            st_wt(&sacc2[2 * 16 + s], ia);
            st_wt(&sacc2[3 * 16 + s], pa);
            st_wt(&sacc2[4 * 16 + s], mxs);
            st_wt(&sacc2[5 * 16 + s], fa);
            st_wti(&vv2[s], vv);
        }
    }
    flag_post(&f4[s], lane);

    // ---------------- phase 4b: final combine in block 0 (16 lane-parallel samples)
    if (blockIdx.x != 0) return;
    for (;;) {
        int v = (lane < NSAMP) ? ld_bpi(&f4[lane]) : 1;
        if (__all(v != 0)) break;
        __builtin_amdgcn_s_sleep(2);
    }
    asm volatile("" ::: "memory");
    float fsum = 0.f, bsum = 0.f, dsum = 0.f, isum = 0.f;
    if (lane < NSAMP) {
        float t1  = ld_bp(&sacc2[0 * 16 + lane]);
        float t2  = ld_bp(&sacc2[1 * 16 + lane]);
        float ia  = ld_bp(&sacc2[2 * 16 + lane]);
        float pa  = ld_bp(&sacc2[3 * 16 + lane]);
        float mxs = ld_bp(&sacc2[4 * 16 + lane]);
        float fa  = ld_bp(&sacc2[5 * 16 + lane]);
        int   vv  = ld_bpi(&vv2[lane]);
        bool hasb = (vv & 3) == 3;     // boundary nonempty (has_fg && has_bg)
        fsum = fa;
        float distsum = hasb ? ((mxs > 0.f) ? t2 / fmaxf(mxs, 1e-12f) : 0.f) : t1;
        bsum = t1 + distsum;
        dsum = (2.f * ia + 1e-6f) / (pa + 1e-6f);
        isum = (ia + 1e-6f) / (pa - ia + 1e-6f);
    }
#pragma unroll
    for (int off = 32; off > 0; off >>= 1) {
        fsum += __shfl_xor(fsum, off);
        bsum += __shfl_xor(bsum, off);
        dsum += __shfl_xor(dsum, off);
        isum += __shfl_xor(isum, off);
    }
    if (lane == 0) {
        float focal = fsum / NTOT_F;
        float bnd   = bsum / NTOT_F;
        float dice = 1.f - dsum / 16.f;
        float iou  = 1.f - isum / 16.f;
        float l0 = lv[0], l1 = lv[1], l2 = lv[2], l3 = lv[3];
        float total = expf(-l0) * focal + l0 + expf(-l1) * dice + l1
                    + expf(-l2) * bnd  + l2 + expf(-l3) * iou  + l3;
        out[0] = total; out[1] = focal; out[2] = dice; out[3] = bnd; out[4] = iou;
    }
}

extern "C" void kernel_launch(void* const* d_in, const int* in_sizes, int n_in,
                              void* d_out, int out_size, void* d_ws, size_t ws_size,
                              hipStream_t stream) {
    const float* pred = (const float*)d_in[0];
    const int*   tg   = (const int*)d_in[1];
    const float* lv   = (const float*)d_in[2];
    float* out = (float*)d_out;
    char* ws = (char*)d_ws;
    int*   f1       = (int*)(ws + OFF_F1);
    int*   f2       = (int*)(ws + OFF_F2);
    int*   f3       = (int*)(ws + OFF_F3);
    int*   f4       = (int*)(ws + OFF_F4);
    int*   blkflags = (int*)(ws + OFF_FLAGS);
    float* sacc     = (float*)(ws + OFF_SACC);
    float* mmax1    = (float*)(ws + OFF_MMAX1);
    float* mmax2    = (float*)(ws + OFF_MMAX2);
    float* sacc2    = (float*)(ws + OFF_SACC2);
    int*   vv2      = (int*)(ws + OFF_VV2);
    float* Llast    = (float*)(ws + OFF_LLAST);
    float* Llast2   = (float*)(ws + OFF_LLAST2);

    // ws is poisoned between iterations -> flags (f1,f2,f3,f4) must be zeroed.
    hipMemsetAsync(ws, 0, 24704, stream);
    fused_kernel<<<NBLK, 64, 0, stream>>>(pred, tg, lv, out, Llast, mmax1, blkflags,
                                          Llast2, mmax2, sacc, f1, f2, f3, f4,
                                          sacc2, vv2);
}